// Round 7
// baseline (471.885 us; speedup 1.0000x reference)
//
#include <hip/hip_runtime.h>
#include <hip/hip_bf16.h>

// ---------------------------------------------------------------------------
// 3-layer GAT (eval mode) on MI355X.
//   L1: alpha = X@(W1@a) ; Xagg = softmax-gather of X (128ch) ;
//       f1 = ELU(Xagg @ W1 + b1)  (per-head fused GEMM)
//   L2: h2 = f1@W2 ; alpha from h2 ; per-head gather of h2 (+b2, ELU)
//   L3: h3 = f2@W3 ; alpha ; gather 64ch (+b3)
// ---------------------------------------------------------------------------

typedef __attribute__((ext_vector_type(8))) short bf16x8;
typedef __attribute__((ext_vector_type(4))) float f32x4;

__device__ __forceinline__ float bflo(unsigned w) { return __uint_as_float(w << 16); }
__device__ __forceinline__ float bfhi(unsigned w) { return __uint_as_float(w & 0xffff0000u); }
__device__ __forceinline__ float leaky(float x) { return x > 0.f ? x : 0.2f * x; }
__device__ __forceinline__ unsigned pack2(float a, float b) {
    unsigned ua = __bfloat16_as_ushort(__float2bfloat16(a));
    unsigned ub = __bfloat16_as_ushort(__float2bfloat16(b));
    return ua | (ub << 16);
}

// ------------------------- CSR build ---------------------------------------

__global__ void k_count(const int* __restrict__ ei, int E, int N, int* __restrict__ cnt) {
    int e = blockIdx.x * blockDim.x + threadIdx.x;
    int tot = E + N;
    if (e >= tot) return;
    int d = (e < E) ? ei[E + e] : (e - E);
    atomicAdd(&cnt[d], 1);
}

// scan of padded counts cp = (cnt+3)&~3
__global__ void k_scan1(const int* __restrict__ cnt, int N, int* __restrict__ rp,
                        int* __restrict__ blksum) {
    __shared__ int sdata[256];
    int t = threadIdx.x;
    int base = blockIdx.x * 1024;
    int v[4];
    int loc = 0;
#pragma unroll
    for (int i = 0; i < 4; i++) {
        int idx = base + t * 4 + i;
        v[i] = (idx < N) ? ((cnt[idx] + 3) & ~3) : 0;
        loc += v[i];
    }
    int x = loc;
    sdata[t] = x;
    __syncthreads();
    for (int off = 1; off < 256; off <<= 1) {
        int y = (t >= off) ? sdata[t - off] : 0;
        __syncthreads();
        x += y;
        sdata[t] = x;
        __syncthreads();
    }
    int run = x - loc;
#pragma unroll
    for (int i = 0; i < 4; i++) {
        int idx = base + t * 4 + i;
        if (idx < N) rp[idx] = run;
        run += v[i];
    }
    if (t == 255) blksum[blockIdx.x] = x;
}

__global__ void k_scan2(const int* __restrict__ blksum, int nblk, int* __restrict__ blkoff) {
    int l = threadIdx.x;
    int v = (l < nblk) ? blksum[l] : 0;
    int x = v;
#pragma unroll
    for (int off = 1; off < 64; off <<= 1) {
        int y = __shfl_up(x, off);
        if (l >= off) x += y;
    }
    if (l < nblk) blkoff[l] = x - v;
}

// finalize rp, init cur, and fill pad slots (col=0 w=0 sentinel dste=-1)
__global__ void k_scan3(int* __restrict__ rp, const int* __restrict__ blkoff,
                        const int* __restrict__ blksum, const int* __restrict__ cnt,
                        int N, int nblk, int* __restrict__ cur,
                        int* __restrict__ col, int* __restrict__ dste) {
    int i = blockIdx.x * blockDim.x + threadIdx.x;
    if (i < N) {
        int v = rp[i] + blkoff[i >> 10];
        rp[i] = v;
        cur[i] = v;
        int c = cnt[i];
        int pad = ((c + 3) & ~3) - c;
        for (int p = 0; p < pad; p++) {
            col[v + c + p] = 0;
            dste[v + c + p] = -1;
        }
    }
    if (i == 0) rp[N] = blkoff[nblk - 1] + blksum[nblk - 1];
}

__global__ void k_fill(const int* __restrict__ ei, int E, int N, int* __restrict__ cur,
                       int* __restrict__ col, int* __restrict__ dste) {
    int e = blockIdx.x * blockDim.x + threadIdx.x;
    int tot = E + N;
    if (e >= tot) return;
    int s, d;
    if (e < E) { s = ei[e]; d = ei[E + e]; }
    else       { s = e - E; d = e - E; }
    int p = atomicAdd(&cur[d], 1);
    col[p] = s;
    dste[p] = d;
}

// ------------------------- casts & small precomputes ------------------------

__global__ void k_cast_pad(const float* __restrict__ X, __hip_bfloat16* __restrict__ Xb,
                           int n_elems, int total) {
    int i = (blockIdx.x * blockDim.x + threadIdx.x) * 4;
    if (i >= total) return;
    float4 v = make_float4(0.f, 0.f, 0.f, 0.f);
    if (i < n_elems) v = *(const float4*)&X[i];
    __hip_bfloat16 tmp[4] = {__float2bfloat16(v.x), __float2bfloat16(v.y),
                             __float2bfloat16(v.z), __float2bfloat16(v.w)};
    *(ushort4*)&Xb[i] = *(const ushort4*)tmp;
}

__global__ void k_castT(const float* __restrict__ W, __hip_bfloat16* __restrict__ Wt,
                        int K, int Nw) {
    __shared__ float t[32][33];
    int k0 = blockIdx.x * 32, n0 = blockIdx.y * 32;
    int tx = threadIdx.x & 31, ty = threadIdx.x >> 5;
    for (int i = ty; i < 32; i += 8) t[i][tx] = W[(size_t)(k0 + i) * Nw + n0 + tx];
    __syncthreads();
    for (int i = ty; i < 32; i += 8)
        Wt[(size_t)(n0 + i) * K + k0 + tx] = __float2bfloat16(t[tx][i]);
}

// va8[c][0..3] = (W1[c, h*128:]·a_src[h]),  va8[c][4..7] = same with a_dst.
__global__ void k_va1(const float* __restrict__ W1, const float* __restrict__ asrc,
                      const float* __restrict__ adst, float* __restrict__ va8) {
    int t = threadIdx.x;        // 512 threads: c = t>>2, h = t&3
    int c = t >> 2, h = t & 3;
    const float* wrow = W1 + (size_t)c * 512 + h * 128;
    const float* av = asrc + h * 128;
    const float* dv = adst + h * 128;
    float vs = 0.f, vd = 0.f;
    for (int k = 0; k < 128; k++) {
        float wv = wrow[k];
        vs += wv * av[k];
        vd += wv * dv[k];
    }
    va8[c * 8 + h] = vs;
    va8[c * 8 + 4 + h] = vd;
}

// alpha for layer 1 straight from X (bf16): one wave per node.
__global__ void k_alpha_x(const __hip_bfloat16* __restrict__ xb,
                          const float* __restrict__ va8, float* __restrict__ as_out,
                          float* __restrict__ ad_out, int N) {
    int w = (blockIdx.x * blockDim.x + threadIdx.x) >> 6;
    int lane = threadIdx.x & 63;
    if (w >= N) return;
    unsigned wrd = ((const unsigned*)xb)[(size_t)w * 64 + lane];
    float f0 = bflo(wrd), f1 = bfhi(wrd);
    int c0 = lane * 2;
    float4 vs0 = *(const float4*)&va8[c0 * 8];
    float4 vd0 = *(const float4*)&va8[c0 * 8 + 4];
    float4 vs1 = *(const float4*)&va8[(c0 + 1) * 8];
    float4 vd1 = *(const float4*)&va8[(c0 + 1) * 8 + 4];
    float s[8];
    s[0] = f0 * vs0.x + f1 * vs1.x;
    s[1] = f0 * vs0.y + f1 * vs1.y;
    s[2] = f0 * vs0.z + f1 * vs1.z;
    s[3] = f0 * vs0.w + f1 * vs1.w;
    s[4] = f0 * vd0.x + f1 * vd1.x;
    s[5] = f0 * vd0.y + f1 * vd1.y;
    s[6] = f0 * vd0.z + f1 * vd1.z;
    s[7] = f0 * vd0.w + f1 * vd1.w;
#pragma unroll
    for (int off = 32; off >= 1; off >>= 1)
#pragma unroll
        for (int j = 0; j < 8; j++) s[j] += __shfl_xor(s[j], off);
    if (lane == 0) {
        *(float4*)&as_out[w * 4] = make_float4(s[0], s[1], s[2], s[3]);
        *(float4*)&ad_out[w * 4] = make_float4(s[4], s[5], s[6], s[7]);
    }
}

// ------------------------- bf16 MFMA GEMM ----------------------------------
// C[row, cbase+col] = A[row, :K] @ Bt[col, :K]^T ; optional fused bias+ELU.
// blockIdx.z selects head block via hsA/hsB/hsC offsets.

template <int BN, bool FUSE>
__global__ void __launch_bounds__(256) k_gemm_mfma(const __hip_bfloat16* __restrict__ A,
                                                   const __hip_bfloat16* __restrict__ Bt,
                                                   __hip_bfloat16* __restrict__ C,
                                                   int lda, int ldc, int K,
                                                   int hsA, int hsB, int hsC,
                                                   const float* __restrict__ bias) {
    constexpr int BM = 128, BK = 64;
    constexpr int WM = 64;
    constexpr int WN = BN / 2;
    constexpr int MREP = WM / 16;
    constexpr int NREP = WN / 16;

    __shared__ __hip_bfloat16 lds[(BM + BN) * BK];
    __hip_bfloat16* As = lds;
    __hip_bfloat16* Bs = lds + BM * BK;

    const int z = blockIdx.z;
    A += (size_t)z * hsA;
    Bt += (size_t)z * hsB;
    const int cbase = z * hsC;

    const int tid = threadIdx.x;
    const int wave = tid >> 6;
    const int lane = tid & 63;
    const int wm0 = (wave >> 1) * WM;
    const int wn0 = (wave & 1) * WN;
    const int m0 = blockIdx.y * BM;
    const int n0 = blockIdx.x * BN;
    const int fr = lane & 15;
    const int fq = lane >> 4;

    f32x4 acc[MREP][NREP] = {};

    for (int kt = 0; kt < K; kt += BK) {
        const __hip_bfloat16* srcA = A + (size_t)m0 * lda + kt;
#pragma unroll
        for (int it = 0; it < BM * 8 / 256; ++it) {
            int gb = it * 256 + wave * 64;
            int g = gb + lane;
            int row = g >> 3;
            int kg = (g & 7) ^ (row & 7);
            const __hip_bfloat16* gsrc = srcA + (size_t)row * lda + kg * 8;
            __builtin_amdgcn_global_load_lds(
                (const __attribute__((address_space(1))) void*)gsrc,
                (__attribute__((address_space(3))) void*)(As + gb * 8), 16, 0, 0);
        }
        const __hip_bfloat16* srcB = Bt + (size_t)n0 * K + kt;
#pragma unroll
        for (int it = 0; it < BN * 8 / 256; ++it) {
            int gb = it * 256 + wave * 64;
            int g = gb + lane;
            int row = g >> 3;
            int kg = (g & 7) ^ (row & 7);
            const __hip_bfloat16* gsrc = srcB + (size_t)row * K + kg * 8;
            __builtin_amdgcn_global_load_lds(
                (const __attribute__((address_space(1))) void*)gsrc,
                (__attribute__((address_space(3))) void*)(Bs + gb * 8), 16, 0, 0);
        }
        __syncthreads();

#pragma unroll
        for (int sl = 0; sl < 2; ++sl) {
            int ke = sl * 32 + fq * 8;
            bf16x8 af[MREP], bfr[NREP];
#pragma unroll
            for (int i = 0; i < MREP; ++i) {
                int row = wm0 + i * 16 + fr;
                int e = (row * BK + ke) ^ ((row & 7) << 3);
                af[i] = *(const bf16x8*)(As + e);
            }
#pragma unroll
            for (int j = 0; j < NREP; ++j) {
                int row = wn0 + j * 16 + fr;
                int e = (row * BK + ke) ^ ((row & 7) << 3);
                bfr[j] = *(const bf16x8*)(Bs + e);
            }
#pragma unroll
            for (int i = 0; i < MREP; ++i)
#pragma unroll
                for (int j = 0; j < NREP; ++j)
                    acc[i][j] = __builtin_amdgcn_mfma_f32_16x16x32_bf16(
                        af[i], bfr[j], acc[i][j], 0, 0, 0);
        }
        __syncthreads();
    }

#pragma unroll
    for (int i = 0; i < MREP; ++i) {
#pragma unroll
        for (int j = 0; j < NREP; ++j) {
            int colg = cbase + n0 + wn0 + j * 16 + fr;
#pragma unroll
            for (int r = 0; r < 4; ++r) {
                int rowg = m0 + wm0 + i * 16 + fq * 4 + r;
                float v = acc[i][j][r];
                if (FUSE) {
                    v += bias[colg];
                    v = v > 0.f ? v : expm1f(v);
                }
                C[(size_t)rowg * ldc + colg] = __float2bfloat16(v);
            }
        }
    }
}

// ------------------------- per-node attention logits (from bf16 h) ----------

template <int C, int H>
__global__ void k_alpha(const __hip_bfloat16* __restrict__ h, const float* __restrict__ a_src,
                        const float* __restrict__ a_dst, float* __restrict__ as_out,
                        float* __restrict__ ad_out, int N) {
    int w = (blockIdx.x * blockDim.x + threadIdx.x) >> 6;
    int lane = threadIdx.x & 63;
    int n = w / H, hd = w % H;
    if (n >= N) return;
    const __hip_bfloat16* hp = h + (size_t)n * (C * H) + hd * C;
    const float* asp = a_src + hd * C;
    const float* adp = a_dst + hd * C;
    float s1 = 0.f, s2 = 0.f;
    if constexpr (C == 128) {
        unsigned wrd = *(const unsigned*)(hp + 2 * lane);
        float f0 = bflo(wrd), f1 = bfhi(wrd);
        float2 a2 = *(const float2*)(asp + 2 * lane);
        float2 d2 = *(const float2*)(adp + 2 * lane);
        s1 = f0 * a2.x + f1 * a2.y;
        s2 = f0 * d2.x + f1 * d2.y;
    } else {  // C == 64
        float v = __bfloat162float(hp[lane & 63]);
        s1 = v * asp[lane];
        s2 = v * adp[lane];
    }
#pragma unroll
    for (int off = 32; off >= 1; off >>= 1) {
        s1 += __shfl_xor(s1, off);
        s2 += __shfl_xor(s2, off);
    }
    if (lane == 0) {
        as_out[n * H + hd] = s1;
        ad_out[n * H + hd] = s2;
    }
}

// ------------------------- per-edge unnormalized weights --------------------
// AoS float4 per edge (L1 gather-X needs all heads per lane).

__global__ void k_edgewA(const int* __restrict__ col, const int* __restrict__ dste,
                         const float* __restrict__ as, const float* __restrict__ ad,
                         float* __restrict__ wA, const int* __restrict__ rp, int N) {
    int e = blockIdx.x * blockDim.x + threadIdx.x;
    if (e >= rp[N]) return;
    int d = dste[e];
    if (d < 0) {
        *(float4*)&wA[e * 4] = make_float4(0.f, 0.f, 0.f, 0.f);
        return;
    }
    int s = col[e];
    float4 a = *(const float4*)&as[s * 4];
    float4 b = *(const float4*)&ad[d * 4];
    float4 w;
    w.x = __expf(leaky(a.x + b.x));
    w.y = __expf(leaky(a.y + b.y));
    w.z = __expf(leaky(a.z + b.z));
    w.w = __expf(leaky(a.w + b.w));
    *(float4*)&wA[e * 4] = w;
}

// SoA planes (L2 per-head gather reads one plane).

__global__ void k_edgewS(const int* __restrict__ col, const int* __restrict__ dste,
                         const float* __restrict__ as, const float* __restrict__ ad,
                         float* __restrict__ wS, const int* __restrict__ rp, int N, int EP) {
    int e = blockIdx.x * blockDim.x + threadIdx.x;
    if (e >= rp[N]) return;
    int d = dste[e];
    if (d < 0) {
        wS[e] = 0.f; wS[EP + e] = 0.f; wS[2 * EP + e] = 0.f; wS[3 * EP + e] = 0.f;
        return;
    }
    int s = col[e];
    float4 a = *(const float4*)&as[s * 4];
    float4 b = *(const float4*)&ad[d * 4];
    wS[e]          = __expf(leaky(a.x + b.x));
    wS[EP + e]     = __expf(leaky(a.y + b.y));
    wS[2 * EP + e] = __expf(leaky(a.z + b.z));
    wS[3 * EP + e] = __expf(leaky(a.w + b.w));
}

__global__ void k_edgew1(const int* __restrict__ col, const int* __restrict__ dste,
                         const float* __restrict__ as, const float* __restrict__ ad,
                         float* __restrict__ wS, const int* __restrict__ rp, int N) {
    int e = blockIdx.x * blockDim.x + threadIdx.x;
    if (e >= rp[N]) return;
    int d = dste[e];
    if (d < 0) { wS[e] = 0.f; return; }
    wS[e] = __expf(leaky(as[col[e]] + ad[d]));
}

// ------------------------- gathers ------------------------------------------
// L1: gather X rows (128 ch bf16); one wave per dst; lane owns 2 channels,
// accumulates all 4 heads. Output normalized Xagg [N][4*128] bf16.

__global__ void k_gatherX(const __hip_bfloat16* __restrict__ xb,
                          const float* __restrict__ wA, const int* __restrict__ rp,
                          const int* __restrict__ col, unsigned* __restrict__ out32, int N) {
    int w = (blockIdx.x * blockDim.x + threadIdx.x) >> 6;
    int lane = threadIdx.x & 63;
    if (w >= N) return;
    int d = w;
    int r0 = rp[d], r1 = rp[d + 1];
    const unsigned* xp = (const unsigned*)xb;

    float acc[8] = {};
    float ws0 = 0.f, ws1 = 0.f, ws2 = 0.f, ws3 = 0.f;
    for (int e = r0; e < r1; e += 4) {
        int4 c4 = *(const int4*)&col[e];
        float4 w0 = *(const float4*)&wA[e * 4];
        float4 w1 = *(const float4*)&wA[e * 4 + 4];
        float4 w2 = *(const float4*)&wA[e * 4 + 8];
        float4 w3 = *(const float4*)&wA[e * 4 + 12];
        unsigned v0 = xp[(size_t)c4.x * 64 + lane];
        unsigned v1 = xp[(size_t)c4.y * 64 + lane];
        unsigned v2 = xp[(size_t)c4.z * 64 + lane];
        unsigned v3 = xp[(size_t)c4.w * 64 + lane];
        ws0 += w0.x + w1.x + w2.x + w3.x;
        ws1 += w0.y + w1.y + w2.y + w3.y;
        ws2 += w0.z + w1.z + w2.z + w3.z;
        ws3 += w0.w + w1.w + w2.w + w3.w;
        float f0, f1;
        f0 = bflo(v0); f1 = bfhi(v0);
        acc[0] += w0.x * f0; acc[1] += w0.x * f1;
        acc[2] += w0.y * f0; acc[3] += w0.y * f1;
        acc[4] += w0.z * f0; acc[5] += w0.z * f1;
        acc[6] += w0.w * f0; acc[7] += w0.w * f1;
        f0 = bflo(v1); f1 = bfhi(v1);
        acc[0] += w1.x * f0; acc[1] += w1.x * f1;
        acc[2] += w1.y * f0; acc[3] += w1.y * f1;
        acc[4] += w1.z * f0; acc[5] += w1.z * f1;
        acc[6] += w1.w * f0; acc[7] += w1.w * f1;
        f0 = bflo(v2); f1 = bfhi(v2);
        acc[0] += w2.x * f0; acc[1] += w2.x * f1;
        acc[2] += w2.y * f0; acc[3] += w2.y * f1;
        acc[4] += w2.z * f0; acc[5] += w2.z * f1;
        acc[6] += w2.w * f0; acc[7] += w2.w * f1;
        f0 = bflo(v3); f1 = bfhi(v3);
        acc[0] += w3.x * f0; acc[1] += w3.x * f1;
        acc[2] += w3.y * f0; acc[3] += w3.y * f1;
        acc[4] += w3.z * f0; acc[5] += w3.z * f1;
        acc[6] += w3.w * f0; acc[7] += w3.w * f1;
    }
    float i0 = 1.f / (ws0 + 1e-16f), i1 = 1.f / (ws1 + 1e-16f);
    float i2 = 1.f / (ws2 + 1e-16f), i3 = 1.f / (ws3 + 1e-16f);
    size_t ob = (size_t)d * 256 + lane;
    out32[ob]       = pack2(acc[0] * i0, acc[1] * i0);
    out32[ob + 64]  = pack2(acc[2] * i1, acc[3] * i1);
    out32[ob + 128] = pack2(acc[4] * i2, acc[5] * i2);
    out32[ob + 192] = pack2(acc[6] * i3, acc[7] * i3);
}

// L2: per-head gather of h2 (blockIdx.z = head).
// 16 lanes per row-slice x uint4 (16B) per lane; 4 edges in flight across the
// 4 lane-groups; shfl_xor(16,32) tail reduce; uint4 packed-bf16 store.

__global__ void k_gatherH(const __hip_bfloat16* __restrict__ hfeat,
                          const float* __restrict__ wS, const int* __restrict__ rp,
                          const int* __restrict__ col, const float* __restrict__ bias,
                          uint4* __restrict__ out4, int N, int EP) {
    int w = (blockIdx.x * blockDim.x + threadIdx.x) >> 6;
    int lane = threadIdx.x & 63;
    if (w >= N) return;
    int hd = blockIdx.z;
    int d = w;
    int r0 = rp[d], r1 = rp[d + 1];      // both %4 == 0
    int g = lane >> 4, cl = lane & 15;   // edge slot / channel quad
    const float* wp = wS + (size_t)hd * EP;
    const uint4* hp = (const uint4*)hfeat;           // row stride 64 uint4
    const unsigned soff = (unsigned)(hd * 16 + cl);  // slice offset in row

    float acc[8] = {};
    float wsum = 0.f;
    for (int e0 = r0; e0 < r1; e0 += 4) {
        int e = e0 + g;
        int s = col[e];
        float wf = wp[e];
        uint4 v = hp[(unsigned)s * 64u + soff];
        wsum += wf;
        acc[0] += wf * bflo(v.x); acc[1] += wf * bfhi(v.x);
        acc[2] += wf * bflo(v.y); acc[3] += wf * bfhi(v.y);
        acc[4] += wf * bflo(v.z); acc[5] += wf * bfhi(v.z);
        acc[6] += wf * bflo(v.w); acc[7] += wf * bfhi(v.w);
    }
#pragma unroll
    for (int off = 16; off <= 32; off <<= 1) {
#pragma unroll
        for (int j = 0; j < 8; j++) acc[j] += __shfl_xor(acc[j], off);
        wsum += __shfl_xor(wsum, off);
    }
    if (g == 0) {
        float inv = 1.f / (wsum + 1e-16f);
        int c = hd * 128 + cl * 8;
        float o[8];
#pragma unroll
        for (int j = 0; j < 8; j++) {
            float v = acc[j] * inv + bias[c + j];
            o[j] = v > 0.f ? v : expm1f(v);
        }
        out4[(size_t)d * 64 + soff] =
            make_uint4(pack2(o[0], o[1]), pack2(o[2], o[3]),
                       pack2(o[4], o[5]), pack2(o[6], o[7]));
    }
}

// L3: CT=64, H=1, f32 out: 16-lane groups each handle one edge, 4 edges/iter.

__global__ void k_gather64(const __hip_bfloat16* __restrict__ hfeat,
                           const float* __restrict__ wbuf, const int* __restrict__ rp,
                           const int* __restrict__ col, const float* __restrict__ bias,
                           float* __restrict__ out, int N) {
    int w = (blockIdx.x * blockDim.x + threadIdx.x) >> 6;
    int lane = threadIdx.x & 63;
    if (w >= N) return;
    int d = w;
    int r0 = rp[d], r1 = rp[d + 1];
    int g = lane >> 4, cl = lane & 15;

    float a0 = 0.f, a1 = 0.f, a2 = 0.f, a3 = 0.f, wsum = 0.f;
    for (int e0 = r0; e0 < r1; e0 += 4) {
        int e = e0 + g;
        int s = col[e];
        float wf = wbuf[e];
        uint2 q = *(const uint2*)(hfeat + (size_t)s * 64 + cl * 4);
        wsum += wf;
        a0 += wf * bflo(q.x);
        a1 += wf * bfhi(q.x);
        a2 += wf * bflo(q.y);
        a3 += wf * bfhi(q.y);
    }
#pragma unroll
    for (int off = 16; off <= 32; off <<= 1) {
        a0 += __shfl_xor(a0, off);
        a1 += __shfl_xor(a1, off);
        a2 += __shfl_xor(a2, off);
        a3 += __shfl_xor(a3, off);
        wsum += __shfl_xor(wsum, off);
    }
    if (g == 0) {
        float inv = 1.0f / (wsum + 1e-16f);
        float4 b4 = *(const float4*)&bias[cl * 4];
        float4 o = make_float4(a0 * inv + b4.x, a1 * inv + b4.y,
                               a2 * inv + b4.z, a3 * inv + b4.w);
        *(float4*)(out + (size_t)d * 64 + cl * 4) = o;
    }
}

// ------------------------- host launcher ------------------------------------

extern "C" void kernel_launch(void* const* d_in, const int* in_sizes, int n_in,
                              void* d_out, int out_size, void* d_ws, size_t ws_size,
                              hipStream_t stream) {
    const float* x   = (const float*)d_in[0];
    const int*   ei  = (const int*)d_in[1];
    const float* W1  = (const float*)d_in[2];
    const float* as1 = (const float*)d_in[3];
    const float* ad1 = (const float*)d_in[4];
    const float* b1  = (const float*)d_in[5];
    const float* W2  = (const float*)d_in[6];
    const float* as2 = (const float*)d_in[7];
    const float* ad2 = (const float*)d_in[8];
    const float* b2  = (const float*)d_in[9];
    const float* W3  = (const float*)d_in[10];
    const float* as3 = (const float*)d_in[11];
    const float* ad3 = (const float*)d_in[12];
    const float* b3  = (const float*)d_in[13];

    const int N = in_sizes[0] / 128;     // 50000
    const int E = in_sizes[1] / 2;       // 400000
    const int Etot = E + N;
    const int EP = (Etot + 3 * N + 255) & ~255;  // padded-edge upper bound
    const int Mp = (N + 127) & ~127;     // 50048

    char* ws = (char*)d_ws;
    size_t off = 0;
    auto alloc = [&](size_t bytes) -> void* {
        void* p = ws + off;
        off = (off + bytes + 255) & ~(size_t)255;
        return p;
    };
    __hip_bfloat16* hbuf = (__hip_bfloat16*)alloc((size_t)Mp * 512 * 2);  // h2 / h3
    __hip_bfloat16* fbuf = (__hip_bfloat16*)alloc((size_t)Mp * 512 * 2);  // f1 / f2
    __hip_bfloat16* xagg = (__hip_bfloat16*)alloc((size_t)Mp * 512 * 2);  // L1 gathered X
    __hip_bfloat16* xb   = (__hip_bfloat16*)alloc((size_t)Mp * 128 * 2);
    __hip_bfloat16* Wt1  = (__hip_bfloat16*)alloc((size_t)512 * 128 * 2);
    __hip_bfloat16* Wt2  = (__hip_bfloat16*)alloc((size_t)512 * 512 * 2);
    __hip_bfloat16* Wt3  = (__hip_bfloat16*)alloc((size_t)64 * 512 * 2);
    float* aS   = (float*)alloc((size_t)N * 4 * 4);
    float* aD   = (float*)alloc((size_t)N * 4 * 4);
    float* wbuf = (float*)alloc((size_t)EP * 4 * 4);   // AoS (L1) or SoA (L2/L3)
    float* va8  = (float*)alloc(128 * 8 * 4);
    int* cnt  = (int*)alloc((size_t)N * 4);
    int* rp   = (int*)alloc((size_t)(N + 1) * 4);
    int* cur  = (int*)alloc((size_t)N * 4);
    int* col  = (int*)alloc((size_t)EP * 4);
    int* dste = (int*)alloc((size_t)EP * 4);
    int* blks = (int*)alloc(64 * 4);
    int* blko = (int*)alloc(64 * 4);

    // ---- CSR build (padded) ----
    hipMemsetAsync(cnt, 0, (size_t)N * 4, stream);
    int thr = 256;
    k_count<<<(Etot + thr - 1) / thr, thr, 0, stream>>>(ei, E, N, cnt);
    int nblk = (N + 1023) / 1024;
    k_scan1<<<nblk, 256, 0, stream>>>(cnt, N, rp, blks);
    k_scan2<<<1, 64, 0, stream>>>(blks, nblk, blko);
    k_scan3<<<(N + 255) / 256, 256, 0, stream>>>(rp, blko, blks, cnt, N, nblk, cur, col, dste);
    k_fill<<<(Etot + thr - 1) / thr, thr, 0, stream>>>(ei, E, N, cur, col, dste);

    // ---- one-time casts + va ----
    {
        int total = Mp * 128;
        k_cast_pad<<<(total / 4 + 255) / 256, 256, 0, stream>>>(x, xb, N * 128, total);
        dim3 g1(128 / 32, 512 / 32);
        k_castT<<<g1, 256, 0, stream>>>(W1, Wt1, 128, 512);
        dim3 g2(512 / 32, 512 / 32);
        k_castT<<<g2, 256, 0, stream>>>(W2, Wt2, 512, 512);
        dim3 g3(512 / 32, 64 / 32);
        k_castT<<<g3, 256, 0, stream>>>(W3, Wt3, 512, 64);
        k_va1<<<1, 512, 0, stream>>>(W1, as1, ad1, va8);
    }

    int alphaBlocks4 = (int)(((size_t)N * 4 * 64 + 255) / 256);
    int alphaBlocks1 = (int)(((size_t)N * 64 + 255) / 256);
    int edgeBlocks = (EP + 255) / 256;
    int gatBlocks = (N + 3) / 4;

    // ---- Layer 1: alpha from X, gather X, fused per-head GEMM ----
    k_alpha_x<<<gatBlocks, 256, 0, stream>>>(xb, va8, aS, aD, N);
    k_edgewA<<<edgeBlocks, 256, 0, stream>>>(col, dste, aS, aD, wbuf, rp, N);
    k_gatherX<<<gatBlocks, 256, 0, stream>>>(xb, wbuf, rp, col, (unsigned*)xagg, N);
    {
        dim3 g(1, Mp / 128, 4);  // z = head
        k_gemm_mfma<128, true><<<g, 256, 0, stream>>>(xagg, Wt1, fbuf,
                                                      512, 512, 128,
                                                      128, 128 * 128, 128, b1);
    }

    // ---- Layer 2: full GEMM, alpha, per-head gather (+b2, ELU) ----
    {
        dim3 g(4, Mp / 128, 1);
        k_gemm_mfma<128, false><<<g, 256, 0, stream>>>(fbuf, Wt2, hbuf,
                                                       512, 512, 512, 0, 0, 0, nullptr);
    }
    k_alpha<128, 4><<<alphaBlocks4, 256, 0, stream>>>(hbuf, as2, ad2, aS, aD, N);
    k_edgewS<<<edgeBlocks, 256, 0, stream>>>(col, dste, aS, aD, wbuf, rp, N, EP);
    {
        dim3 g(gatBlocks, 1, 4);  // z = head (x-major dispatch ~ temporal split)
        k_gatherH<<<g, 256, 0, stream>>>(hbuf, wbuf, rp, col, b2, (uint4*)fbuf, N, EP);
    }

    // ---- Layer 3: GEMM, alpha, gather 64ch (+b3) ----
    {
        dim3 g(1, Mp / 128, 1);
        k_gemm_mfma<64, false><<<g, 256, 0, stream>>>(fbuf, Wt3, hbuf,
                                                      512, 64, 512, 0, 0, 0, nullptr);
    }
    k_alpha<64, 1><<<alphaBlocks1, 256, 0, stream>>>(hbuf, as3, ad3, aS, aD, N);
    k_edgew1<<<edgeBlocks, 256, 0, stream>>>(col, dste, aS, aD, wbuf, rp, N);
    k_gather64<<<gatBlocks, 256, 0, stream>>>(hbuf, wbuf, rp, col, b3, (float*)d_out, N);
}

// Round 8
// 416.738 us; speedup vs baseline: 1.1323x; 1.1323x over previous
//
#include <hip/hip_runtime.h>
#include <hip/hip_bf16.h>

// ---------------------------------------------------------------------------
// 3-layer GAT (eval mode) on MI355X.
//   L1: alpha = X@(W1@a) ; Xagg = softmax-gather of X (128ch) ;
//       f1 = ELU(Xagg @ W1 + b1)  (per-head fused GEMM)
//   L2: h2 = f1@W2 ; alpha from h2 ; full-row gather of h2, software-pipelined
//   L3: h3 = f2@W3 ; alpha ; gather 64ch (+b3)
// ---------------------------------------------------------------------------

typedef __attribute__((ext_vector_type(8))) short bf16x8;
typedef __attribute__((ext_vector_type(4))) float f32x4;

__device__ __forceinline__ float bflo(unsigned w) { return __uint_as_float(w << 16); }
__device__ __forceinline__ float bfhi(unsigned w) { return __uint_as_float(w & 0xffff0000u); }
__device__ __forceinline__ float leaky(float x) { return x > 0.f ? x : 0.2f * x; }
__device__ __forceinline__ unsigned pack2(float a, float b) {
    unsigned ua = __bfloat16_as_ushort(__float2bfloat16(a));
    unsigned ub = __bfloat16_as_ushort(__float2bfloat16(b));
    return ua | (ub << 16);
}

// ------------------------- CSR build ---------------------------------------

__global__ void k_count(const int* __restrict__ ei, int E, int N, int* __restrict__ cnt) {
    int e = blockIdx.x * blockDim.x + threadIdx.x;
    int tot = E + N;
    if (e >= tot) return;
    int d = (e < E) ? ei[E + e] : (e - E);
    atomicAdd(&cnt[d], 1);
}

// scan of padded counts cp = (cnt+3)&~3
__global__ void k_scan1(const int* __restrict__ cnt, int N, int* __restrict__ rp,
                        int* __restrict__ blksum) {
    __shared__ int sdata[256];
    int t = threadIdx.x;
    int base = blockIdx.x * 1024;
    int v[4];
    int loc = 0;
#pragma unroll
    for (int i = 0; i < 4; i++) {
        int idx = base + t * 4 + i;
        v[i] = (idx < N) ? ((cnt[idx] + 3) & ~3) : 0;
        loc += v[i];
    }
    int x = loc;
    sdata[t] = x;
    __syncthreads();
    for (int off = 1; off < 256; off <<= 1) {
        int y = (t >= off) ? sdata[t - off] : 0;
        __syncthreads();
        x += y;
        sdata[t] = x;
        __syncthreads();
    }
    int run = x - loc;
#pragma unroll
    for (int i = 0; i < 4; i++) {
        int idx = base + t * 4 + i;
        if (idx < N) rp[idx] = run;
        run += v[i];
    }
    if (t == 255) blksum[blockIdx.x] = x;
}

__global__ void k_scan2(const int* __restrict__ blksum, int nblk, int* __restrict__ blkoff) {
    int l = threadIdx.x;
    int v = (l < nblk) ? blksum[l] : 0;
    int x = v;
#pragma unroll
    for (int off = 1; off < 64; off <<= 1) {
        int y = __shfl_up(x, off);
        if (l >= off) x += y;
    }
    if (l < nblk) blkoff[l] = x - v;
}

// finalize rp, init cur, and fill pad slots (col=0 w=0 sentinel dste=-1)
__global__ void k_scan3(int* __restrict__ rp, const int* __restrict__ blkoff,
                        const int* __restrict__ blksum, const int* __restrict__ cnt,
                        int N, int nblk, int* __restrict__ cur,
                        int* __restrict__ col, int* __restrict__ dste) {
    int i = blockIdx.x * blockDim.x + threadIdx.x;
    if (i < N) {
        int v = rp[i] + blkoff[i >> 10];
        rp[i] = v;
        cur[i] = v;
        int c = cnt[i];
        int pad = ((c + 3) & ~3) - c;
        for (int p = 0; p < pad; p++) {
            col[v + c + p] = 0;
            dste[v + c + p] = -1;
        }
    }
    if (i == 0) rp[N] = blkoff[nblk - 1] + blksum[nblk - 1];
}

__global__ void k_fill(const int* __restrict__ ei, int E, int N, int* __restrict__ cur,
                       int* __restrict__ col, int* __restrict__ dste) {
    int e = blockIdx.x * blockDim.x + threadIdx.x;
    int tot = E + N;
    if (e >= tot) return;
    int s, d;
    if (e < E) { s = ei[e]; d = ei[E + e]; }
    else       { s = e - E; d = e - E; }
    int p = atomicAdd(&cur[d], 1);
    col[p] = s;
    dste[p] = d;
}

// ------------------------- casts & small precomputes ------------------------

__global__ void k_cast_pad(const float* __restrict__ X, __hip_bfloat16* __restrict__ Xb,
                           int n_elems, int total) {
    int i = (blockIdx.x * blockDim.x + threadIdx.x) * 4;
    if (i >= total) return;
    float4 v = make_float4(0.f, 0.f, 0.f, 0.f);
    if (i < n_elems) v = *(const float4*)&X[i];
    __hip_bfloat16 tmp[4] = {__float2bfloat16(v.x), __float2bfloat16(v.y),
                             __float2bfloat16(v.z), __float2bfloat16(v.w)};
    *(ushort4*)&Xb[i] = *(const ushort4*)tmp;
}

__global__ void k_castT(const float* __restrict__ W, __hip_bfloat16* __restrict__ Wt,
                        int K, int Nw) {
    __shared__ float t[32][33];
    int k0 = blockIdx.x * 32, n0 = blockIdx.y * 32;
    int tx = threadIdx.x & 31, ty = threadIdx.x >> 5;
    for (int i = ty; i < 32; i += 8) t[i][tx] = W[(size_t)(k0 + i) * Nw + n0 + tx];
    __syncthreads();
    for (int i = ty; i < 32; i += 8)
        Wt[(size_t)(n0 + i) * K + k0 + tx] = __float2bfloat16(t[tx][i]);
}

// va8[c][0..3] = (W1[c, h*128:]·a_src[h]),  va8[c][4..7] = same with a_dst.
__global__ void k_va1(const float* __restrict__ W1, const float* __restrict__ asrc,
                      const float* __restrict__ adst, float* __restrict__ va8) {
    int t = threadIdx.x;        // 512 threads: c = t>>2, h = t&3
    int c = t >> 2, h = t & 3;
    const float* wrow = W1 + (size_t)c * 512 + h * 128;
    const float* av = asrc + h * 128;
    const float* dv = adst + h * 128;
    float vs = 0.f, vd = 0.f;
    for (int k = 0; k < 128; k++) {
        float wv = wrow[k];
        vs += wv * av[k];
        vd += wv * dv[k];
    }
    va8[c * 8 + h] = vs;
    va8[c * 8 + 4 + h] = vd;
}

// alpha for layer 1 straight from X (bf16): one wave per node.
__global__ void k_alpha_x(const __hip_bfloat16* __restrict__ xb,
                          const float* __restrict__ va8, float* __restrict__ as_out,
                          float* __restrict__ ad_out, int N) {
    int w = (blockIdx.x * blockDim.x + threadIdx.x) >> 6;
    int lane = threadIdx.x & 63;
    if (w >= N) return;
    unsigned wrd = ((const unsigned*)xb)[(size_t)w * 64 + lane];
    float f0 = bflo(wrd), f1 = bfhi(wrd);
    int c0 = lane * 2;
    float4 vs0 = *(const float4*)&va8[c0 * 8];
    float4 vd0 = *(const float4*)&va8[c0 * 8 + 4];
    float4 vs1 = *(const float4*)&va8[(c0 + 1) * 8];
    float4 vd1 = *(const float4*)&va8[(c0 + 1) * 8 + 4];
    float s[8];
    s[0] = f0 * vs0.x + f1 * vs1.x;
    s[1] = f0 * vs0.y + f1 * vs1.y;
    s[2] = f0 * vs0.z + f1 * vs1.z;
    s[3] = f0 * vs0.w + f1 * vs1.w;
    s[4] = f0 * vd0.x + f1 * vd1.x;
    s[5] = f0 * vd0.y + f1 * vd1.y;
    s[6] = f0 * vd0.z + f1 * vd1.z;
    s[7] = f0 * vd0.w + f1 * vd1.w;
#pragma unroll
    for (int off = 32; off >= 1; off >>= 1)
#pragma unroll
        for (int j = 0; j < 8; j++) s[j] += __shfl_xor(s[j], off);
    if (lane == 0) {
        *(float4*)&as_out[w * 4] = make_float4(s[0], s[1], s[2], s[3]);
        *(float4*)&ad_out[w * 4] = make_float4(s[4], s[5], s[6], s[7]);
    }
}

// ------------------------- bf16 MFMA GEMM ----------------------------------
// C[row, cbase+col] = A[row, :K] @ Bt[col, :K]^T ; optional fused bias+ELU.
// blockIdx.z selects head block via hsA/hsB/hsC offsets.

template <int BN, bool FUSE>
__global__ void __launch_bounds__(256) k_gemm_mfma(const __hip_bfloat16* __restrict__ A,
                                                   const __hip_bfloat16* __restrict__ Bt,
                                                   __hip_bfloat16* __restrict__ C,
                                                   int lda, int ldc, int K,
                                                   int hsA, int hsB, int hsC,
                                                   const float* __restrict__ bias) {
    constexpr int BM = 128, BK = 64;
    constexpr int WM = 64;
    constexpr int WN = BN / 2;
    constexpr int MREP = WM / 16;
    constexpr int NREP = WN / 16;

    __shared__ __hip_bfloat16 lds[(BM + BN) * BK];
    __hip_bfloat16* As = lds;
    __hip_bfloat16* Bs = lds + BM * BK;

    const int z = blockIdx.z;
    A += (size_t)z * hsA;
    Bt += (size_t)z * hsB;
    const int cbase = z * hsC;

    const int tid = threadIdx.x;
    const int wave = tid >> 6;
    const int lane = tid & 63;
    const int wm0 = (wave >> 1) * WM;
    const int wn0 = (wave & 1) * WN;
    const int m0 = blockIdx.y * BM;
    const int n0 = blockIdx.x * BN;
    const int fr = lane & 15;
    const int fq = lane >> 4;

    f32x4 acc[MREP][NREP] = {};

    for (int kt = 0; kt < K; kt += BK) {
        const __hip_bfloat16* srcA = A + (size_t)m0 * lda + kt;
#pragma unroll
        for (int it = 0; it < BM * 8 / 256; ++it) {
            int gb = it * 256 + wave * 64;
            int g = gb + lane;
            int row = g >> 3;
            int kg = (g & 7) ^ (row & 7);
            const __hip_bfloat16* gsrc = srcA + (size_t)row * lda + kg * 8;
            __builtin_amdgcn_global_load_lds(
                (const __attribute__((address_space(1))) void*)gsrc,
                (__attribute__((address_space(3))) void*)(As + gb * 8), 16, 0, 0);
        }
        const __hip_bfloat16* srcB = Bt + (size_t)n0 * K + kt;
#pragma unroll
        for (int it = 0; it < BN * 8 / 256; ++it) {
            int gb = it * 256 + wave * 64;
            int g = gb + lane;
            int row = g >> 3;
            int kg = (g & 7) ^ (row & 7);
            const __hip_bfloat16* gsrc = srcB + (size_t)row * K + kg * 8;
            __builtin_amdgcn_global_load_lds(
                (const __attribute__((address_space(1))) void*)gsrc,
                (__attribute__((address_space(3))) void*)(Bs + gb * 8), 16, 0, 0);
        }
        __syncthreads();

#pragma unroll
        for (int sl = 0; sl < 2; ++sl) {
            int ke = sl * 32 + fq * 8;
            bf16x8 af[MREP], bfr[NREP];
#pragma unroll
            for (int i = 0; i < MREP; ++i) {
                int row = wm0 + i * 16 + fr;
                int e = (row * BK + ke) ^ ((row & 7) << 3);
                af[i] = *(const bf16x8*)(As + e);
            }
#pragma unroll
            for (int j = 0; j < NREP; ++j) {
                int row = wn0 + j * 16 + fr;
                int e = (row * BK + ke) ^ ((row & 7) << 3);
                bfr[j] = *(const bf16x8*)(Bs + e);
            }
#pragma unroll
            for (int i = 0; i < MREP; ++i)
#pragma unroll
                for (int j = 0; j < NREP; ++j)
                    acc[i][j] = __builtin_amdgcn_mfma_f32_16x16x32_bf16(
                        af[i], bfr[j], acc[i][j], 0, 0, 0);
        }
        __syncthreads();
    }

#pragma unroll
    for (int i = 0; i < MREP; ++i) {
#pragma unroll
        for (int j = 0; j < NREP; ++j) {
            int colg = cbase + n0 + wn0 + j * 16 + fr;
#pragma unroll
            for (int r = 0; r < 4; ++r) {
                int rowg = m0 + wm0 + i * 16 + fq * 4 + r;
                float v = acc[i][j][r];
                if (FUSE) {
                    v += bias[colg];
                    v = v > 0.f ? v : expm1f(v);
                }
                C[(size_t)rowg * ldc + colg] = __float2bfloat16(v);
            }
        }
    }
}

// ------------------------- per-node attention logits (from bf16 h) ----------

template <int C, int H>
__global__ void k_alpha(const __hip_bfloat16* __restrict__ h, const float* __restrict__ a_src,
                        const float* __restrict__ a_dst, float* __restrict__ as_out,
                        float* __restrict__ ad_out, int N) {
    int w = (blockIdx.x * blockDim.x + threadIdx.x) >> 6;
    int lane = threadIdx.x & 63;
    int n = w / H, hd = w % H;
    if (n >= N) return;
    const __hip_bfloat16* hp = h + (size_t)n * (C * H) + hd * C;
    const float* asp = a_src + hd * C;
    const float* adp = a_dst + hd * C;
    float s1 = 0.f, s2 = 0.f;
    if constexpr (C == 128) {
        unsigned wrd = *(const unsigned*)(hp + 2 * lane);
        float f0 = bflo(wrd), f1 = bfhi(wrd);
        float2 a2 = *(const float2*)(asp + 2 * lane);
        float2 d2 = *(const float2*)(adp + 2 * lane);
        s1 = f0 * a2.x + f1 * a2.y;
        s2 = f0 * d2.x + f1 * d2.y;
    } else {  // C == 64
        float v = __bfloat162float(hp[lane & 63]);
        s1 = v * asp[lane];
        s2 = v * adp[lane];
    }
#pragma unroll
    for (int off = 32; off >= 1; off >>= 1) {
        s1 += __shfl_xor(s1, off);
        s2 += __shfl_xor(s2, off);
    }
    if (lane == 0) {
        as_out[n * H + hd] = s1;
        ad_out[n * H + hd] = s2;
    }
}

// ------------------------- per-edge unnormalized weights --------------------
// AoS float4 per edge (L1 gather-X needs all heads per lane).

__global__ void k_edgewA(const int* __restrict__ col, const int* __restrict__ dste,
                         const float* __restrict__ as, const float* __restrict__ ad,
                         float* __restrict__ wA, const int* __restrict__ rp, int N) {
    int e = blockIdx.x * blockDim.x + threadIdx.x;
    if (e >= rp[N]) return;
    int d = dste[e];
    if (d < 0) {
        *(float4*)&wA[e * 4] = make_float4(0.f, 0.f, 0.f, 0.f);
        return;
    }
    int s = col[e];
    float4 a = *(const float4*)&as[s * 4];
    float4 b = *(const float4*)&ad[d * 4];
    float4 w;
    w.x = __expf(leaky(a.x + b.x));
    w.y = __expf(leaky(a.y + b.y));
    w.z = __expf(leaky(a.z + b.z));
    w.w = __expf(leaky(a.w + b.w));
    *(float4*)&wA[e * 4] = w;
}

// SoA planes (L2 gather reads one plane per lane-group).

__global__ void k_edgewS(const int* __restrict__ col, const int* __restrict__ dste,
                         const float* __restrict__ as, const float* __restrict__ ad,
                         float* __restrict__ wS, const int* __restrict__ rp, int N, int EP) {
    int e = blockIdx.x * blockDim.x + threadIdx.x;
    if (e >= rp[N]) return;
    int d = dste[e];
    if (d < 0) {
        wS[e] = 0.f; wS[EP + e] = 0.f; wS[2 * EP + e] = 0.f; wS[3 * EP + e] = 0.f;
        return;
    }
    int s = col[e];
    float4 a = *(const float4*)&as[s * 4];
    float4 b = *(const float4*)&ad[d * 4];
    wS[e]          = __expf(leaky(a.x + b.x));
    wS[EP + e]     = __expf(leaky(a.y + b.y));
    wS[2 * EP + e] = __expf(leaky(a.z + b.z));
    wS[3 * EP + e] = __expf(leaky(a.w + b.w));
}

__global__ void k_edgew1(const int* __restrict__ col, const int* __restrict__ dste,
                         const float* __restrict__ as, const float* __restrict__ ad,
                         float* __restrict__ wS, const int* __restrict__ rp, int N) {
    int e = blockIdx.x * blockDim.x + threadIdx.x;
    if (e >= rp[N]) return;
    int d = dste[e];
    if (d < 0) { wS[e] = 0.f; return; }
    wS[e] = __expf(leaky(as[col[e]] + ad[d]));
}

// ------------------------- gathers ------------------------------------------
// L1: gather X rows (128 ch bf16); one wave per dst; lane owns 2 channels,
// accumulates all 4 heads. Output normalized Xagg [N][4*128] bf16.

__global__ void k_gatherX(const __hip_bfloat16* __restrict__ xb,
                          const float* __restrict__ wA, const int* __restrict__ rp,
                          const int* __restrict__ col, unsigned* __restrict__ out32, int N) {
    int w = (blockIdx.x * blockDim.x + threadIdx.x) >> 6;
    int lane = threadIdx.x & 63;
    if (w >= N) return;
    int d = w;
    int r0 = rp[d], r1 = rp[d + 1];
    const unsigned* xp = (const unsigned*)xb;

    float acc[8] = {};
    float ws0 = 0.f, ws1 = 0.f, ws2 = 0.f, ws3 = 0.f;
    for (int e = r0; e < r1; e += 4) {
        int4 c4 = *(const int4*)&col[e];
        float4 w0 = *(const float4*)&wA[e * 4];
        float4 w1 = *(const float4*)&wA[e * 4 + 4];
        float4 w2 = *(const float4*)&wA[e * 4 + 8];
        float4 w3 = *(const float4*)&wA[e * 4 + 12];
        unsigned v0 = xp[(size_t)c4.x * 64 + lane];
        unsigned v1 = xp[(size_t)c4.y * 64 + lane];
        unsigned v2 = xp[(size_t)c4.z * 64 + lane];
        unsigned v3 = xp[(size_t)c4.w * 64 + lane];
        ws0 += w0.x + w1.x + w2.x + w3.x;
        ws1 += w0.y + w1.y + w2.y + w3.y;
        ws2 += w0.z + w1.z + w2.z + w3.z;
        ws3 += w0.w + w1.w + w2.w + w3.w;
        float f0, f1;
        f0 = bflo(v0); f1 = bfhi(v0);
        acc[0] += w0.x * f0; acc[1] += w0.x * f1;
        acc[2] += w0.y * f0; acc[3] += w0.y * f1;
        acc[4] += w0.z * f0; acc[5] += w0.z * f1;
        acc[6] += w0.w * f0; acc[7] += w0.w * f1;
        f0 = bflo(v1); f1 = bfhi(v1);
        acc[0] += w1.x * f0; acc[1] += w1.x * f1;
        acc[2] += w1.y * f0; acc[3] += w1.y * f1;
        acc[4] += w1.z * f0; acc[5] += w1.z * f1;
        acc[6] += w1.w * f0; acc[7] += w1.w * f1;
        f0 = bflo(v2); f1 = bfhi(v2);
        acc[0] += w2.x * f0; acc[1] += w2.x * f1;
        acc[2] += w2.y * f0; acc[3] += w2.y * f1;
        acc[4] += w2.z * f0; acc[5] += w2.z * f1;
        acc[6] += w2.w * f0; acc[7] += w2.w * f1;
        f0 = bflo(v3); f1 = bfhi(v3);
        acc[0] += w3.x * f0; acc[1] += w3.x * f1;
        acc[2] += w3.y * f0; acc[3] += w3.y * f1;
        acc[4] += w3.z * f0; acc[5] += w3.z * f1;
        acc[6] += w3.w * f0; acc[7] += w3.w * f1;
    }
    float i0 = 1.f / (ws0 + 1e-16f), i1 = 1.f / (ws1 + 1e-16f);
    float i2 = 1.f / (ws2 + 1e-16f), i3 = 1.f / (ws3 + 1e-16f);
    size_t ob = (size_t)d * 256 + lane;
    out32[ob]       = pack2(acc[0] * i0, acc[1] * i0);
    out32[ob + 64]  = pack2(acc[2] * i1, acc[3] * i1);
    out32[ob + 128] = pack2(acc[4] * i2, acc[5] * i2);
    out32[ob + 192] = pack2(acc[6] * i3, acc[7] * i3);
}

// L2: full-row gather of h2 (512 ch), one wave per node, 16B/lane, 2-deep
// software pipeline: while FMA-ing quad i, issue quad i+1's row loads and
// quad i+2's index/weight loads (clamped addresses; over-fetch never used).

template <bool DO_ELU>
__global__ void k_gather512(const __hip_bfloat16* __restrict__ hfeat,
                            const float* __restrict__ wS, const int* __restrict__ rp,
                            const int* __restrict__ col, const float* __restrict__ bias,
                            __hip_bfloat16* __restrict__ out, int N, int EP) {
    int w = (blockIdx.x * blockDim.x + threadIdx.x) >> 6;
    int lane = threadIdx.x & 63;
    if (w >= N) return;
    int d = w;
    int r0 = rp[d], r1 = rp[d + 1];  // quad-aligned, r1-r0 >= 4
    const float* wp = wS + (size_t)(lane >> 4) * EP;  // my head's weight plane
    const uint4* hp = (const uint4*)hfeat;            // 64 uint4 per 512-ch row

    float acc[8] = {};
    float wsum = 0.f;

    // pipeline prologue: quad0 rows + quad1 indices
    int4 cA = *(const int4*)&col[r0];
    float4 wq = *(const float4*)&wp[r0];
    uint4 vA0 = hp[(size_t)cA.x * 64 + lane];
    uint4 vA1 = hp[(size_t)cA.y * 64 + lane];
    uint4 vA2 = hp[(size_t)cA.z * 64 + lane];
    uint4 vA3 = hp[(size_t)cA.w * 64 + lane];
    int eB = (r0 + 4 < r1) ? r0 + 4 : r0;
    int4 cB = *(const int4*)&col[eB];
    float4 wqB = *(const float4*)&wp[eB];

    for (int e = r0; e < r1; e += 4) {
        int eC = (e + 8 < r1) ? e + 8 : r0;  // clamped (never consumed if OOR)
        // issue next-quad row loads
        uint4 nb0 = hp[(size_t)cB.x * 64 + lane];
        uint4 nb1 = hp[(size_t)cB.y * 64 + lane];
        uint4 nb2 = hp[(size_t)cB.z * 64 + lane];
        uint4 nb3 = hp[(size_t)cB.w * 64 + lane];
        // issue quad-after-next index/weight loads
        int4 cC = *(const int4*)&col[eC];
        float4 wqC = *(const float4*)&wp[eC];

        // compute current quad
        wsum += (wq.x + wq.y) + (wq.z + wq.w);
        acc[0] += wq.x * bflo(vA0.x); acc[1] += wq.x * bfhi(vA0.x);
        acc[2] += wq.x * bflo(vA0.y); acc[3] += wq.x * bfhi(vA0.y);
        acc[4] += wq.x * bflo(vA0.z); acc[5] += wq.x * bfhi(vA0.z);
        acc[6] += wq.x * bflo(vA0.w); acc[7] += wq.x * bfhi(vA0.w);
        acc[0] += wq.y * bflo(vA1.x); acc[1] += wq.y * bfhi(vA1.x);
        acc[2] += wq.y * bflo(vA1.y); acc[3] += wq.y * bfhi(vA1.y);
        acc[4] += wq.y * bflo(vA1.z); acc[5] += wq.y * bfhi(vA1.z);
        acc[6] += wq.y * bflo(vA1.w); acc[7] += wq.y * bfhi(vA1.w);
        acc[0] += wq.z * bflo(vA2.x); acc[1] += wq.z * bfhi(vA2.x);
        acc[2] += wq.z * bflo(vA2.y); acc[3] += wq.z * bfhi(vA2.y);
        acc[4] += wq.z * bflo(vA2.z); acc[5] += wq.z * bfhi(vA2.z);
        acc[6] += wq.z * bflo(vA2.w); acc[7] += wq.z * bfhi(vA2.w);
        acc[0] += wq.w * bflo(vA3.x); acc[1] += wq.w * bfhi(vA3.x);
        acc[2] += wq.w * bflo(vA3.y); acc[3] += wq.w * bfhi(vA3.y);
        acc[4] += wq.w * bflo(vA3.z); acc[5] += wq.w * bfhi(vA3.z);
        acc[6] += wq.w * bflo(vA3.w); acc[7] += wq.w * bfhi(vA3.w);

        // shift pipeline
        wq = wqB; wqB = wqC; cB = cC;
        vA0 = nb0; vA1 = nb1; vA2 = nb2; vA3 = nb3;
    }

    float inv = 1.0f / (wsum + 1e-16f);
    __hip_bfloat16 tmp[8];
#pragma unroll
    for (int j = 0; j < 8; j++) {
        float v = acc[j] * inv + bias[lane * 8 + j];
        if (DO_ELU) v = v > 0.f ? v : expm1f(v);
        tmp[j] = __float2bfloat16(v);
    }
    *(float4*)(out + (size_t)d * 512 + lane * 8) = *(const float4*)tmp;
}

// L3: CT=64, H=1, f32 out: 16-lane groups each handle one edge, 4 edges/iter.

__global__ void k_gather64(const __hip_bfloat16* __restrict__ hfeat,
                           const float* __restrict__ wbuf, const int* __restrict__ rp,
                           const int* __restrict__ col, const float* __restrict__ bias,
                           float* __restrict__ out, int N) {
    int w = (blockIdx.x * blockDim.x + threadIdx.x) >> 6;
    int lane = threadIdx.x & 63;
    if (w >= N) return;
    int d = w;
    int r0 = rp[d], r1 = rp[d + 1];
    int g = lane >> 4, cl = lane & 15;

    float a0 = 0.f, a1 = 0.f, a2 = 0.f, a3 = 0.f, wsum = 0.f;
    for (int e0 = r0; e0 < r1; e0 += 4) {
        int e = e0 + g;
        int s = col[e];
        float wf = wbuf[e];
        uint2 q = *(const uint2*)(hfeat + (size_t)s * 64 + cl * 4);
        wsum += wf;
        a0 += wf * bflo(q.x);
        a1 += wf * bfhi(q.x);
        a2 += wf * bflo(q.y);
        a3 += wf * bfhi(q.y);
    }
#pragma unroll
    for (int off = 16; off <= 32; off <<= 1) {
        a0 += __shfl_xor(a0, off);
        a1 += __shfl_xor(a1, off);
        a2 += __shfl_xor(a2, off);
        a3 += __shfl_xor(a3, off);
        wsum += __shfl_xor(wsum, off);
    }
    if (g == 0) {
        float inv = 1.0f / (wsum + 1e-16f);
        float4 b4 = *(const float4*)&bias[cl * 4];
        float4 o = make_float4(a0 * inv + b4.x, a1 * inv + b4.y,
                               a2 * inv + b4.z, a3 * inv + b4.w);
        *(float4*)(out + (size_t)d * 64 + cl * 4) = o;
    }
}

// ------------------------- host launcher ------------------------------------

extern "C" void kernel_launch(void* const* d_in, const int* in_sizes, int n_in,
                              void* d_out, int out_size, void* d_ws, size_t ws_size,
                              hipStream_t stream) {
    const float* x   = (const float*)d_in[0];
    const int*   ei  = (const int*)d_in[1];
    const float* W1  = (const float*)d_in[2];
    const float* as1 = (const float*)d_in[3];
    const float* ad1 = (const float*)d_in[4];
    const float* b1  = (const float*)d_in[5];
    const float* W2  = (const float*)d_in[6];
    const float* as2 = (const float*)d_in[7];
    const float* ad2 = (const float*)d_in[8];
    const float* b2  = (const float*)d_in[9];
    const float* W3  = (const float*)d_in[10];
    const float* as3 = (const float*)d_in[11];
    const float* ad3 = (const float*)d_in[12];
    const float* b3  = (const float*)d_in[13];

    const int N = in_sizes[0] / 128;     // 50000
    const int E = in_sizes[1] / 2;       // 400000
    const int Etot = E + N;
    const int EP = (Etot + 3 * N + 1024 + 255) & ~255;  // padded-edge bound + margin
    const int Mp = (N + 127) & ~127;     // 50048

    char* ws = (char*)d_ws;
    size_t off = 0;
    auto alloc = [&](size_t bytes) -> void* {
        void* p = ws + off;
        off = (off + bytes + 255) & ~(size_t)255;
        return p;
    };
    __hip_bfloat16* hbuf = (__hip_bfloat16*)alloc((size_t)Mp * 512 * 2);  // h2 / h3
    __hip_bfloat16* fbuf = (__hip_bfloat16*)alloc((size_t)Mp * 512 * 2);  // f1 / f2
    __hip_bfloat16* xagg = (__hip_bfloat16*)alloc((size_t)Mp * 512 * 2);  // L1 gathered X
    __hip_bfloat16* xb   = (__hip_bfloat16*)alloc((size_t)Mp * 128 * 2);
    __hip_bfloat16* Wt1  = (__hip_bfloat16*)alloc((size_t)512 * 128 * 2);
    __hip_bfloat16* Wt2  = (__hip_bfloat16*)alloc((size_t)512 * 512 * 2);
    __hip_bfloat16* Wt3  = (__hip_bfloat16*)alloc((size_t)64 * 512 * 2);
    float* aS   = (float*)alloc((size_t)N * 4 * 4);
    float* aD   = (float*)alloc((size_t)N * 4 * 4);
    float* wbuf = (float*)alloc((size_t)EP * 4 * 4);   // AoS (L1) or SoA (L2/L3)
    float* va8  = (float*)alloc(128 * 8 * 4);
    int* cnt  = (int*)alloc((size_t)N * 4);
    int* rp   = (int*)alloc((size_t)(N + 1) * 4);
    int* cur  = (int*)alloc((size_t)N * 4);
    int* col  = (int*)alloc((size_t)EP * 4);
    int* dste = (int*)alloc((size_t)EP * 4);
    int* blks = (int*)alloc(64 * 4);
    int* blko = (int*)alloc(64 * 4);

    // ---- CSR build (padded) ----
    hipMemsetAsync(cnt, 0, (size_t)N * 4, stream);
    int thr = 256;
    k_count<<<(Etot + thr - 1) / thr, thr, 0, stream>>>(ei, E, N, cnt);
    int nblk = (N + 1023) / 1024;
    k_scan1<<<nblk, 256, 0, stream>>>(cnt, N, rp, blks);
    k_scan2<<<1, 64, 0, stream>>>(blks, nblk, blko);
    k_scan3<<<(N + 255) / 256, 256, 0, stream>>>(rp, blko, blks, cnt, N, nblk, cur, col, dste);
    k_fill<<<(Etot + thr - 1) / thr, thr, 0, stream>>>(ei, E, N, cur, col, dste);

    // ---- one-time casts + va ----
    {
        int total = Mp * 128;
        k_cast_pad<<<(total / 4 + 255) / 256, 256, 0, stream>>>(x, xb, N * 128, total);
        dim3 g1(128 / 32, 512 / 32);
        k_castT<<<g1, 256, 0, stream>>>(W1, Wt1, 128, 512);
        dim3 g2(512 / 32, 512 / 32);
        k_castT<<<g2, 256, 0, stream>>>(W2, Wt2, 512, 512);
        dim3 g3(512 / 32, 64 / 32);
        k_castT<<<g3, 256, 0, stream>>>(W3, Wt3, 512, 64);
        k_va1<<<1, 512, 0, stream>>>(W1, as1, ad1, va8);
    }

    int alphaBlocks4 = (int)(((size_t)N * 4 * 64 + 255) / 256);
    int alphaBlocks1 = (int)(((size_t)N * 64 + 255) / 256);
    int edgeBlocks = (EP + 255) / 256;
    int gatBlocks = (N + 3) / 4;

    // ---- Layer 1: alpha from X, gather X, fused per-head GEMM ----
    k_alpha_x<<<gatBlocks, 256, 0, stream>>>(xb, va8, aS, aD, N);
    k_edgewA<<<edgeBlocks, 256, 0, stream>>>(col, dste, aS, aD, wbuf, rp, N);
    k_gatherX<<<gatBlocks, 256, 0, stream>>>(xb, wbuf, rp, col, (unsigned*)xagg, N);
    {
        dim3 g(1, Mp / 128, 4);  // z = head
        k_gemm_mfma<128, true><<<g, 256, 0, stream>>>(xagg, Wt1, fbuf,
                                                      512, 512, 128,
                                                      128, 128 * 128, 128, b1);
    }

    // ---- Layer 2: full GEMM, alpha, pipelined full-row gather (+b2, ELU) ----
    {
        dim3 g(4, Mp / 128, 1);
        k_gemm_mfma<128, false><<<g, 256, 0, stream>>>(fbuf, Wt2, hbuf,
                                                       512, 512, 512, 0, 0, 0, nullptr);
    }
    k_alpha<128, 4><<<alphaBlocks4, 256, 0, stream>>>(hbuf, as2, ad2, aS, aD, N);
    k_edgewS<<<edgeBlocks, 256, 0, stream>>>(col, dste, aS, aD, wbuf, rp, N, EP);
    k_gather512<true><<<gatBlocks, 256, 0, stream>>>(hbuf, wbuf, rp, col, b2, fbuf, N, EP);

    // ---- Layer 3: GEMM, alpha, gather 64ch (+b3) ----
    {
        dim3 g(1, Mp / 128, 1);
        k_gemm_mfma<64, false><<<g, 256, 0, stream>>>(fbuf, Wt3, hbuf,
                                                      512, 64, 512, 0, 0, 0, nullptr);
    }
    k_alpha<64, 1><<<alphaBlocks1, 256, 0, stream>>>(hbuf, as3, ad3, aS, aD, N);
    k_edgew1<<<edgeBlocks, 256, 0, stream>>>(col, dste, aS, aD, wbuf, rp, N);
    k_gather64<<<gatBlocks, 256, 0, stream>>>(hbuf, wbuf, rp, col, b3, (float*)d_out, N);
}

// Round 9
// 408.223 us; speedup vs baseline: 1.1559x; 1.0209x over previous
//
#include <hip/hip_runtime.h>
#include <hip/hip_bf16.h>

// ---------------------------------------------------------------------------
// 3-layer GAT (eval mode) on MI355X.
//   L1: alpha = X@(W1@a) ; Xagg = softmax-gather of X (128ch) ;
//       f1 = ELU(Xagg @ W1 + b1)  (per-head fused GEMM)
//   L2: h2 = f1@W2 ; alpha from h2 ; full-row gather of h2 w/ inline weights
//   L3: h3 = f2@W3 ; alpha ; gather 64ch w/ inline weights (+b3)
// ---------------------------------------------------------------------------

typedef __attribute__((ext_vector_type(8))) short bf16x8;
typedef __attribute__((ext_vector_type(4))) float f32x4;

__device__ __forceinline__ float bflo(unsigned w) { return __uint_as_float(w << 16); }
__device__ __forceinline__ float bfhi(unsigned w) { return __uint_as_float(w & 0xffff0000u); }
__device__ __forceinline__ float leaky(float x) { return x > 0.f ? x : 0.2f * x; }
__device__ __forceinline__ unsigned pack2(float a, float b) {
    unsigned ua = __bfloat16_as_ushort(__float2bfloat16(a));
    unsigned ub = __bfloat16_as_ushort(__float2bfloat16(b));
    return ua | (ub << 16);
}

// ------------------------- CSR build ---------------------------------------

__global__ void k_count(const int* __restrict__ ei, int E, int N, int* __restrict__ cnt) {
    int e = blockIdx.x * blockDim.x + threadIdx.x;
    int tot = E + N;
    if (e >= tot) return;
    int d = (e < E) ? ei[E + e] : (e - E);
    atomicAdd(&cnt[d], 1);
}

// scan of padded counts cp = (cnt+3)&~3
__global__ void k_scan1(const int* __restrict__ cnt, int N, int* __restrict__ rp,
                        int* __restrict__ blksum) {
    __shared__ int sdata[256];
    int t = threadIdx.x;
    int base = blockIdx.x * 1024;
    int v[4];
    int loc = 0;
#pragma unroll
    for (int i = 0; i < 4; i++) {
        int idx = base + t * 4 + i;
        v[i] = (idx < N) ? ((cnt[idx] + 3) & ~3) : 0;
        loc += v[i];
    }
    int x = loc;
    sdata[t] = x;
    __syncthreads();
    for (int off = 1; off < 256; off <<= 1) {
        int y = (t >= off) ? sdata[t - off] : 0;
        __syncthreads();
        x += y;
        sdata[t] = x;
        __syncthreads();
    }
    int run = x - loc;
#pragma unroll
    for (int i = 0; i < 4; i++) {
        int idx = base + t * 4 + i;
        if (idx < N) rp[idx] = run;
        run += v[i];
    }
    if (t == 255) blksum[blockIdx.x] = x;
}

__global__ void k_scan2(const int* __restrict__ blksum, int nblk, int* __restrict__ blkoff) {
    int l = threadIdx.x;
    int v = (l < nblk) ? blksum[l] : 0;
    int x = v;
#pragma unroll
    for (int off = 1; off < 64; off <<= 1) {
        int y = __shfl_up(x, off);
        if (l >= off) x += y;
    }
    if (l < nblk) blkoff[l] = x - v;
}

// finalize rp, init cur, and fill pad slots (col=0, dste=-1)
__global__ void k_scan3(int* __restrict__ rp, const int* __restrict__ blkoff,
                        const int* __restrict__ blksum, const int* __restrict__ cnt,
                        int N, int nblk, int* __restrict__ cur,
                        int* __restrict__ col, int* __restrict__ dste) {
    int i = blockIdx.x * blockDim.x + threadIdx.x;
    if (i < N) {
        int v = rp[i] + blkoff[i >> 10];
        rp[i] = v;
        cur[i] = v;
        int c = cnt[i];
        int pad = ((c + 3) & ~3) - c;
        for (int p = 0; p < pad; p++) {
            col[v + c + p] = 0;
            dste[v + c + p] = -1;
        }
    }
    if (i == 0) rp[N] = blkoff[nblk - 1] + blksum[nblk - 1];
}

__global__ void k_fill(const int* __restrict__ ei, int E, int N, int* __restrict__ cur,
                       int* __restrict__ col, int* __restrict__ dste) {
    int e = blockIdx.x * blockDim.x + threadIdx.x;
    int tot = E + N;
    if (e >= tot) return;
    int s, d;
    if (e < E) { s = ei[e]; d = ei[E + e]; }
    else       { s = e - E; d = e - E; }
    int p = atomicAdd(&cur[d], 1);
    col[p] = s;
    dste[p] = d;
}

// ------------------------- casts & small precomputes ------------------------

__global__ void k_cast_pad(const float* __restrict__ X, __hip_bfloat16* __restrict__ Xb,
                           int n_elems, int total) {
    int i = (blockIdx.x * blockDim.x + threadIdx.x) * 4;
    if (i >= total) return;
    float4 v = make_float4(0.f, 0.f, 0.f, 0.f);
    if (i < n_elems) v = *(const float4*)&X[i];
    __hip_bfloat16 tmp[4] = {__float2bfloat16(v.x), __float2bfloat16(v.y),
                             __float2bfloat16(v.z), __float2bfloat16(v.w)};
    *(ushort4*)&Xb[i] = *(const ushort4*)tmp;
}

__global__ void k_castT(const float* __restrict__ W, __hip_bfloat16* __restrict__ Wt,
                        int K, int Nw) {
    __shared__ float t[32][33];
    int k0 = blockIdx.x * 32, n0 = blockIdx.y * 32;
    int tx = threadIdx.x & 31, ty = threadIdx.x >> 5;
    for (int i = ty; i < 32; i += 8) t[i][tx] = W[(size_t)(k0 + i) * Nw + n0 + tx];
    __syncthreads();
    for (int i = ty; i < 32; i += 8)
        Wt[(size_t)(n0 + i) * K + k0 + tx] = __float2bfloat16(t[tx][i]);
}

// va8[c][0..3] = (W1[c, h*128:]·a_src[h]),  va8[c][4..7] = same with a_dst.
__global__ void k_va1(const float* __restrict__ W1, const float* __restrict__ asrc,
                      const float* __restrict__ adst, float* __restrict__ va8) {
    int t = threadIdx.x;        // 512 threads: c = t>>2, h = t&3
    int c = t >> 2, h = t & 3;
    const float* wrow = W1 + (size_t)c * 512 + h * 128;
    const float* av = asrc + h * 128;
    const float* dv = adst + h * 128;
    float vs = 0.f, vd = 0.f;
    for (int k = 0; k < 128; k++) {
        float wv = wrow[k];
        vs += wv * av[k];
        vd += wv * dv[k];
    }
    va8[c * 8 + h] = vs;
    va8[c * 8 + 4 + h] = vd;
}

// alpha for layer 1 straight from X (bf16): one wave per node.
__global__ void k_alpha_x(const __hip_bfloat16* __restrict__ xb,
                          const float* __restrict__ va8, float* __restrict__ as_out,
                          float* __restrict__ ad_out, int N) {
    int w = (blockIdx.x * blockDim.x + threadIdx.x) >> 6;
    int lane = threadIdx.x & 63;
    if (w >= N) return;
    unsigned wrd = ((const unsigned*)xb)[(size_t)w * 64 + lane];
    float f0 = bflo(wrd), f1 = bfhi(wrd);
    int c0 = lane * 2;
    float4 vs0 = *(const float4*)&va8[c0 * 8];
    float4 vd0 = *(const float4*)&va8[c0 * 8 + 4];
    float4 vs1 = *(const float4*)&va8[(c0 + 1) * 8];
    float4 vd1 = *(const float4*)&va8[(c0 + 1) * 8 + 4];
    float s[8];
    s[0] = f0 * vs0.x + f1 * vs1.x;
    s[1] = f0 * vs0.y + f1 * vs1.y;
    s[2] = f0 * vs0.z + f1 * vs1.z;
    s[3] = f0 * vs0.w + f1 * vs1.w;
    s[4] = f0 * vd0.x + f1 * vd1.x;
    s[5] = f0 * vd0.y + f1 * vd1.y;
    s[6] = f0 * vd0.z + f1 * vd1.z;
    s[7] = f0 * vd0.w + f1 * vd1.w;
#pragma unroll
    for (int off = 32; off >= 1; off >>= 1)
#pragma unroll
        for (int j = 0; j < 8; j++) s[j] += __shfl_xor(s[j], off);
    if (lane == 0) {
        *(float4*)&as_out[w * 4] = make_float4(s[0], s[1], s[2], s[3]);
        *(float4*)&ad_out[w * 4] = make_float4(s[4], s[5], s[6], s[7]);
    }
}

// ------------------------- bf16 MFMA GEMM ----------------------------------
// C[row, cbase+col] = A[row, :K] @ Bt[col, :K]^T ; optional fused bias+ELU.
// blockIdx.z selects head block via hsA/hsB/hsC offsets.

template <int BM, int BN, bool FUSE>
__global__ void __launch_bounds__(256) k_gemm_mfma(const __hip_bfloat16* __restrict__ A,
                                                   const __hip_bfloat16* __restrict__ Bt,
                                                   __hip_bfloat16* __restrict__ C,
                                                   int lda, int ldc, int K,
                                                   int hsA, int hsB, int hsC,
                                                   const float* __restrict__ bias) {
    constexpr int BK = 64;
    constexpr int WM = BM / 2;
    constexpr int WN = BN / 2;
    constexpr int MREP = WM / 16;
    constexpr int NREP = WN / 16;

    __shared__ __hip_bfloat16 lds[(BM + BN) * BK];
    __hip_bfloat16* As = lds;
    __hip_bfloat16* Bs = lds + BM * BK;

    const int z = blockIdx.z;
    A += (size_t)z * hsA;
    Bt += (size_t)z * hsB;
    const int cbase = z * hsC;

    const int tid = threadIdx.x;
    const int wave = tid >> 6;
    const int lane = tid & 63;
    const int wm0 = (wave >> 1) * WM;
    const int wn0 = (wave & 1) * WN;
    const int m0 = blockIdx.y * BM;
    const int n0 = blockIdx.x * BN;
    const int fr = lane & 15;
    const int fq = lane >> 4;

    f32x4 acc[MREP][NREP] = {};

    for (int kt = 0; kt < K; kt += BK) {
        const __hip_bfloat16* srcA = A + (size_t)m0 * lda + kt;
#pragma unroll
        for (int it = 0; it < BM * 8 / 256; ++it) {
            int gb = it * 256 + wave * 64;
            int g = gb + lane;
            int row = g >> 3;
            int kg = (g & 7) ^ (row & 7);
            const __hip_bfloat16* gsrc = srcA + (size_t)row * lda + kg * 8;
            __builtin_amdgcn_global_load_lds(
                (const __attribute__((address_space(1))) void*)gsrc,
                (__attribute__((address_space(3))) void*)(As + gb * 8), 16, 0, 0);
        }
        const __hip_bfloat16* srcB = Bt + (size_t)n0 * K + kt;
#pragma unroll
        for (int it = 0; it < BN * 8 / 256; ++it) {
            int gb = it * 256 + wave * 64;
            int g = gb + lane;
            int row = g >> 3;
            int kg = (g & 7) ^ (row & 7);
            const __hip_bfloat16* gsrc = srcB + (size_t)row * K + kg * 8;
            __builtin_amdgcn_global_load_lds(
                (const __attribute__((address_space(1))) void*)gsrc,
                (__attribute__((address_space(3))) void*)(Bs + gb * 8), 16, 0, 0);
        }
        __syncthreads();

#pragma unroll
        for (int sl = 0; sl < 2; ++sl) {
            int ke = sl * 32 + fq * 8;
            bf16x8 af[MREP], bfr[NREP];
#pragma unroll
            for (int i = 0; i < MREP; ++i) {
                int row = wm0 + i * 16 + fr;
                int e = (row * BK + ke) ^ ((row & 7) << 3);
                af[i] = *(const bf16x8*)(As + e);
            }
#pragma unroll
            for (int j = 0; j < NREP; ++j) {
                int row = wn0 + j * 16 + fr;
                int e = (row * BK + ke) ^ ((row & 7) << 3);
                bfr[j] = *(const bf16x8*)(Bs + e);
            }
#pragma unroll
            for (int i = 0; i < MREP; ++i)
#pragma unroll
                for (int j = 0; j < NREP; ++j)
                    acc[i][j] = __builtin_amdgcn_mfma_f32_16x16x32_bf16(
                        af[i], bfr[j], acc[i][j], 0, 0, 0);
        }
        __syncthreads();
    }

#pragma unroll
    for (int i = 0; i < MREP; ++i) {
#pragma unroll
        for (int j = 0; j < NREP; ++j) {
            int colg = cbase + n0 + wn0 + j * 16 + fr;
#pragma unroll
            for (int r = 0; r < 4; ++r) {
                int rowg = m0 + wm0 + i * 16 + fq * 4 + r;
                float v = acc[i][j][r];
                if (FUSE) {
                    v += bias[colg];
                    v = v > 0.f ? v : expm1f(v);
                }
                C[(size_t)rowg * ldc + colg] = __float2bfloat16(v);
            }
        }
    }
}

// ------------------------- per-node attention logits (from bf16 h) ----------

template <int C, int H>
__global__ void k_alpha(const __hip_bfloat16* __restrict__ h, const float* __restrict__ a_src,
                        const float* __restrict__ a_dst, float* __restrict__ as_out,
                        float* __restrict__ ad_out, int N) {
    int w = (blockIdx.x * blockDim.x + threadIdx.x) >> 6;
    int lane = threadIdx.x & 63;
    int n = w / H, hd = w % H;
    if (n >= N) return;
    const __hip_bfloat16* hp = h + (size_t)n * (C * H) + hd * C;
    const float* asp = a_src + hd * C;
    const float* adp = a_dst + hd * C;
    float s1 = 0.f, s2 = 0.f;
    if constexpr (C == 128) {
        unsigned wrd = *(const unsigned*)(hp + 2 * lane);
        float f0 = bflo(wrd), f1 = bfhi(wrd);
        float2 a2 = *(const float2*)(asp + 2 * lane);
        float2 d2 = *(const float2*)(adp + 2 * lane);
        s1 = f0 * a2.x + f1 * a2.y;
        s2 = f0 * d2.x + f1 * d2.y;
    } else {  // C == 64
        float v = __bfloat162float(hp[lane & 63]);
        s1 = v * asp[lane];
        s2 = v * adp[lane];
    }
#pragma unroll
    for (int off = 32; off >= 1; off >>= 1) {
        s1 += __shfl_xor(s1, off);
        s2 += __shfl_xor(s2, off);
    }
    if (lane == 0) {
        as_out[n * H + hd] = s1;
        ad_out[n * H + hd] = s2;
    }
}

// ------------------------- L1 per-edge weights (AoS) -------------------------

__global__ void k_edgewA(const int* __restrict__ col, const int* __restrict__ dste,
                         const float* __restrict__ as, const float* __restrict__ ad,
                         float* __restrict__ wA, const int* __restrict__ rp, int N) {
    int e = blockIdx.x * blockDim.x + threadIdx.x;
    if (e >= rp[N]) return;
    int d = dste[e];
    if (d < 0) {
        *(float4*)&wA[e * 4] = make_float4(0.f, 0.f, 0.f, 0.f);
        return;
    }
    int s = col[e];
    float4 a = *(const float4*)&as[s * 4];
    float4 b = *(const float4*)&ad[d * 4];
    float4 w;
    w.x = __expf(leaky(a.x + b.x));
    w.y = __expf(leaky(a.y + b.y));
    w.z = __expf(leaky(a.z + b.z));
    w.w = __expf(leaky(a.w + b.w));
    *(float4*)&wA[e * 4] = w;
}

// ------------------------- gathers ------------------------------------------
// L1: gather X rows (128 ch bf16); one wave per dst; lane owns 2 channels,
// accumulates all 4 heads. Output normalized Xagg [N][4*128] bf16.

__global__ void k_gatherX(const __hip_bfloat16* __restrict__ xb,
                          const float* __restrict__ wA, const int* __restrict__ rp,
                          const int* __restrict__ col, unsigned* __restrict__ out32, int N) {
    int w = (blockIdx.x * blockDim.x + threadIdx.x) >> 6;
    int lane = threadIdx.x & 63;
    if (w >= N) return;
    int d = w;
    int r0 = rp[d], r1 = rp[d + 1];
    const unsigned* xp = (const unsigned*)xb;

    float acc[8] = {};
    float ws0 = 0.f, ws1 = 0.f, ws2 = 0.f, ws3 = 0.f;
    for (int e = r0; e < r1; e += 4) {
        int4 c4 = *(const int4*)&col[e];
        float4 w0 = *(const float4*)&wA[e * 4];
        float4 w1 = *(const float4*)&wA[e * 4 + 4];
        float4 w2 = *(const float4*)&wA[e * 4 + 8];
        float4 w3 = *(const float4*)&wA[e * 4 + 12];
        unsigned v0 = xp[(size_t)c4.x * 64 + lane];
        unsigned v1 = xp[(size_t)c4.y * 64 + lane];
        unsigned v2 = xp[(size_t)c4.z * 64 + lane];
        unsigned v3 = xp[(size_t)c4.w * 64 + lane];
        ws0 += w0.x + w1.x + w2.x + w3.x;
        ws1 += w0.y + w1.y + w2.y + w3.y;
        ws2 += w0.z + w1.z + w2.z + w3.z;
        ws3 += w0.w + w1.w + w2.w + w3.w;
        float f0, f1;
        f0 = bflo(v0); f1 = bfhi(v0);
        acc[0] += w0.x * f0; acc[1] += w0.x * f1;
        acc[2] += w0.y * f0; acc[3] += w0.y * f1;
        acc[4] += w0.z * f0; acc[5] += w0.z * f1;
        acc[6] += w0.w * f0; acc[7] += w0.w * f1;
        f0 = bflo(v1); f1 = bfhi(v1);
        acc[0] += w1.x * f0; acc[1] += w1.x * f1;
        acc[2] += w1.y * f0; acc[3] += w1.y * f1;
        acc[4] += w1.z * f0; acc[5] += w1.z * f1;
        acc[6] += w1.w * f0; acc[7] += w1.w * f1;
        f0 = bflo(v2); f1 = bfhi(v2);
        acc[0] += w2.x * f0; acc[1] += w2.x * f1;
        acc[2] += w2.y * f0; acc[3] += w2.y * f1;
        acc[4] += w2.z * f0; acc[5] += w2.z * f1;
        acc[6] += w2.w * f0; acc[7] += w2.w * f1;
        f0 = bflo(v3); f1 = bfhi(v3);
        acc[0] += w3.x * f0; acc[1] += w3.x * f1;
        acc[2] += w3.y * f0; acc[3] += w3.y * f1;
        acc[4] += w3.z * f0; acc[5] += w3.z * f1;
        acc[6] += w3.w * f0; acc[7] += w3.w * f1;
    }
    float i0 = 1.f / (ws0 + 1e-16f), i1 = 1.f / (ws1 + 1e-16f);
    float i2 = 1.f / (ws2 + 1e-16f), i3 = 1.f / (ws3 + 1e-16f);
    size_t ob = (size_t)d * 256 + lane;
    out32[ob]       = pack2(acc[0] * i0, acc[1] * i0);
    out32[ob + 64]  = pack2(acc[2] * i1, acc[3] * i1);
    out32[ob + 128] = pack2(acc[4] * i2, acc[5] * i2);
    out32[ob + 192] = pack2(acc[6] * i3, acc[7] * i3);
}

// L2: full-row gather of h2 (512 ch), one wave per node, 16B/lane, unroll x4.
// Edge weights computed INLINE: w = exp(leaky(as[s,hd] + ad[d,hd])), pad
// slots (e >= r0+cnt[d]) masked to 0.  hd = lane>>4 (16 lanes per head).

template <bool DO_ELU>
__global__ void k_gather512(const __hip_bfloat16* __restrict__ hfeat,
                            const float* __restrict__ as4, const float* __restrict__ ad4,
                            const int* __restrict__ cnt, const int* __restrict__ rp,
                            const int* __restrict__ col, const float* __restrict__ bias,
                            __hip_bfloat16* __restrict__ out, int N) {
    int w = (blockIdx.x * blockDim.x + threadIdx.x) >> 6;
    int lane = threadIdx.x & 63;
    if (w >= N) return;
    int d = w;
    int r0 = rp[d], r1 = rp[d + 1];      // quad-aligned
    int r1r = r0 + cnt[d];               // real edge end
    int hd = lane >> 4;
    float adv = ad4[d * 4 + hd];
    const uint4* hp = (const uint4*)hfeat;  // 64 uint4 per 512-ch row

    float acc[8] = {};
    float wsum = 0.f;
    for (int e = r0; e < r1; e += 4) {
        int4 c4 = *(const int4*)&col[e];
        float l0 = as4[c4.x * 4 + hd] + adv;
        float l1 = as4[c4.y * 4 + hd] + adv;
        float l2 = as4[c4.z * 4 + hd] + adv;
        float l3 = as4[c4.w * 4 + hd] + adv;
        uint4 v0 = hp[(size_t)c4.x * 64 + lane];
        uint4 v1 = hp[(size_t)c4.y * 64 + lane];
        uint4 v2 = hp[(size_t)c4.z * 64 + lane];
        uint4 v3 = hp[(size_t)c4.w * 64 + lane];
        float w0 = (e + 0 < r1r) ? __expf(leaky(l0)) : 0.f;
        float w1 = (e + 1 < r1r) ? __expf(leaky(l1)) : 0.f;
        float w2 = (e + 2 < r1r) ? __expf(leaky(l2)) : 0.f;
        float w3 = (e + 3 < r1r) ? __expf(leaky(l3)) : 0.f;
        wsum += (w0 + w1) + (w2 + w3);
        acc[0] += w0 * bflo(v0.x); acc[1] += w0 * bfhi(v0.x);
        acc[2] += w0 * bflo(v0.y); acc[3] += w0 * bfhi(v0.y);
        acc[4] += w0 * bflo(v0.z); acc[5] += w0 * bfhi(v0.z);
        acc[6] += w0 * bflo(v0.w); acc[7] += w0 * bfhi(v0.w);
        acc[0] += w1 * bflo(v1.x); acc[1] += w1 * bfhi(v1.x);
        acc[2] += w1 * bflo(v1.y); acc[3] += w1 * bfhi(v1.y);
        acc[4] += w1 * bflo(v1.z); acc[5] += w1 * bfhi(v1.z);
        acc[6] += w1 * bflo(v1.w); acc[7] += w1 * bfhi(v1.w);
        acc[0] += w2 * bflo(v2.x); acc[1] += w2 * bfhi(v2.x);
        acc[2] += w2 * bflo(v2.y); acc[3] += w2 * bfhi(v2.y);
        acc[4] += w2 * bflo(v2.z); acc[5] += w2 * bfhi(v2.z);
        acc[6] += w2 * bflo(v2.w); acc[7] += w2 * bfhi(v2.w);
        acc[0] += w3 * bflo(v3.x); acc[1] += w3 * bfhi(v3.x);
        acc[2] += w3 * bflo(v3.y); acc[3] += w3 * bfhi(v3.y);
        acc[4] += w3 * bflo(v3.z); acc[5] += w3 * bfhi(v3.z);
        acc[6] += w3 * bflo(v3.w); acc[7] += w3 * bfhi(v3.w);
    }

    float inv = 1.0f / (wsum + 1e-16f);
    __hip_bfloat16 tmp[8];
#pragma unroll
    for (int j = 0; j < 8; j++) {
        float v = acc[j] * inv + bias[lane * 8 + j];
        if (DO_ELU) v = v > 0.f ? v : expm1f(v);
        tmp[j] = __float2bfloat16(v);
    }
    *(float4*)(out + (size_t)d * 512 + lane * 8) = *(const float4*)tmp;
}

// L3: CT=64, H=1, f32 out: 16-lane groups each handle one edge, 4 edges/iter,
// inline weights (single head), pad masked via cnt.

__global__ void k_gather64(const __hip_bfloat16* __restrict__ hfeat,
                           const float* __restrict__ as1, const float* __restrict__ ad1,
                           const int* __restrict__ cnt, const int* __restrict__ rp,
                           const int* __restrict__ col, const float* __restrict__ bias,
                           float* __restrict__ out, int N) {
    int w = (blockIdx.x * blockDim.x + threadIdx.x) >> 6;
    int lane = threadIdx.x & 63;
    if (w >= N) return;
    int d = w;
    int r0 = rp[d], r1 = rp[d + 1];
    int r1r = r0 + cnt[d];
    float adv = ad1[d];
    int g = lane >> 4, cl = lane & 15;

    float a0 = 0.f, a1 = 0.f, a2 = 0.f, a3 = 0.f, wsum = 0.f;
    for (int e0 = r0; e0 < r1; e0 += 4) {
        int e = e0 + g;
        int s = col[e];
        float l = as1[s] + adv;
        uint2 q = *(const uint2*)(hfeat + (size_t)s * 64 + cl * 4);
        float wf = (e < r1r) ? __expf(leaky(l)) : 0.f;
        wsum += wf;
        a0 += wf * bflo(q.x);
        a1 += wf * bfhi(q.x);
        a2 += wf * bflo(q.y);
        a3 += wf * bfhi(q.y);
    }
#pragma unroll
    for (int off = 16; off <= 32; off <<= 1) {
        a0 += __shfl_xor(a0, off);
        a1 += __shfl_xor(a1, off);
        a2 += __shfl_xor(a2, off);
        a3 += __shfl_xor(a3, off);
        wsum += __shfl_xor(wsum, off);
    }
    if (g == 0) {
        float inv = 1.0f / (wsum + 1e-16f);
        float4 b4 = *(const float4*)&bias[cl * 4];
        float4 o = make_float4(a0 * inv + b4.x, a1 * inv + b4.y,
                               a2 * inv + b4.z, a3 * inv + b4.w);
        *(float4*)(out + (size_t)d * 64 + cl * 4) = o;
    }
}

// ------------------------- host launcher ------------------------------------

extern "C" void kernel_launch(void* const* d_in, const int* in_sizes, int n_in,
                              void* d_out, int out_size, void* d_ws, size_t ws_size,
                              hipStream_t stream) {
    const float* x   = (const float*)d_in[0];
    const int*   ei  = (const int*)d_in[1];
    const float* W1  = (const float*)d_in[2];
    const float* as1 = (const float*)d_in[3];
    const float* ad1 = (const float*)d_in[4];
    const float* b1  = (const float*)d_in[5];
    const float* W2  = (const float*)d_in[6];
    const float* as2 = (const float*)d_in[7];
    const float* ad2 = (const float*)d_in[8];
    const float* b2  = (const float*)d_in[9];
    const float* W3  = (const float*)d_in[10];
    const float* as3 = (const float*)d_in[11];
    const float* ad3 = (const float*)d_in[12];
    const float* b3  = (const float*)d_in[13];

    const int N = in_sizes[0] / 128;     // 50000
    const int E = in_sizes[1] / 2;       // 400000
    const int Etot = E + N;
    const int EP = (Etot + 3 * N + 255) & ~255;  // padded-edge upper bound
    const int Mp = (N + 127) & ~127;     // 50048

    char* ws = (char*)d_ws;
    size_t off = 0;
    auto alloc = [&](size_t bytes) -> void* {
        void* p = ws + off;
        off = (off + bytes + 255) & ~(size_t)255;
        return p;
    };
    __hip_bfloat16* hbuf = (__hip_bfloat16*)alloc((size_t)Mp * 512 * 2);  // h2 / h3
    __hip_bfloat16* fbuf = (__hip_bfloat16*)alloc((size_t)Mp * 512 * 2);  // f1 / f2
    __hip_bfloat16* xagg = (__hip_bfloat16*)alloc((size_t)Mp * 512 * 2);  // L1 gathered X
    __hip_bfloat16* xb   = (__hip_bfloat16*)alloc((size_t)Mp * 128 * 2);
    __hip_bfloat16* Wt1  = (__hip_bfloat16*)alloc((size_t)512 * 128 * 2);
    __hip_bfloat16* Wt2  = (__hip_bfloat16*)alloc((size_t)512 * 512 * 2);
    __hip_bfloat16* Wt3  = (__hip_bfloat16*)alloc((size_t)64 * 512 * 2);
    float* aS   = (float*)alloc((size_t)N * 4 * 4);
    float* aD   = (float*)alloc((size_t)N * 4 * 4);
    float* wbuf = (float*)alloc((size_t)EP * 4 * 4);   // AoS weights (L1 only)
    float* va8  = (float*)alloc(128 * 8 * 4);
    int* cnt  = (int*)alloc((size_t)N * 4);
    int* rp   = (int*)alloc((size_t)(N + 1) * 4);
    int* cur  = (int*)alloc((size_t)N * 4);
    int* col  = (int*)alloc((size_t)EP * 4);
    int* dste = (int*)alloc((size_t)EP * 4);
    int* blks = (int*)alloc(64 * 4);
    int* blko = (int*)alloc(64 * 4);

    // ---- CSR build (padded) ----
    hipMemsetAsync(cnt, 0, (size_t)N * 4, stream);
    int thr = 256;
    k_count<<<(Etot + thr - 1) / thr, thr, 0, stream>>>(ei, E, N, cnt);
    int nblk = (N + 1023) / 1024;
    k_scan1<<<nblk, 256, 0, stream>>>(cnt, N, rp, blks);
    k_scan2<<<1, 64, 0, stream>>>(blks, nblk, blko);
    k_scan3<<<(N + 255) / 256, 256, 0, stream>>>(rp, blko, blks, cnt, N, nblk, cur, col, dste);
    k_fill<<<(Etot + thr - 1) / thr, thr, 0, stream>>>(ei, E, N, cur, col, dste);

    // ---- one-time casts + va ----
    {
        int total = Mp * 128;
        k_cast_pad<<<(total / 4 + 255) / 256, 256, 0, stream>>>(x, xb, N * 128, total);
        dim3 g1(128 / 32, 512 / 32);
        k_castT<<<g1, 256, 0, stream>>>(W1, Wt1, 128, 512);
        dim3 g2(512 / 32, 512 / 32);
        k_castT<<<g2, 256, 0, stream>>>(W2, Wt2, 512, 512);
        dim3 g3(512 / 32, 64 / 32);
        k_castT<<<g3, 256, 0, stream>>>(W3, Wt3, 512, 64);
        k_va1<<<1, 512, 0, stream>>>(W1, as1, ad1, va8);
    }

    int alphaBlocks4 = (int)(((size_t)N * 4 * 64 + 255) / 256);
    int alphaBlocks1 = (int)(((size_t)N * 64 + 255) / 256);
    int edgeBlocks = (EP + 255) / 256;
    int gatBlocks = (N + 3) / 4;

    // ---- Layer 1: alpha from X, gather X, fused per-head GEMM ----
    k_alpha_x<<<gatBlocks, 256, 0, stream>>>(xb, va8, aS, aD, N);
    k_edgewA<<<edgeBlocks, 256, 0, stream>>>(col, dste, aS, aD, wbuf, rp, N);
    k_gatherX<<<gatBlocks, 256, 0, stream>>>(xb, wbuf, rp, col, (unsigned*)xagg, N);
    {
        dim3 g(1, Mp / 128, 4);  // z = head
        k_gemm_mfma<128, 128, true><<<g, 256, 0, stream>>>(xagg, Wt1, fbuf,
                                                           512, 512, 128,
                                                           128, 128 * 128, 128, b1);
    }

    // ---- Layer 2: full GEMM, alpha, full-row gather w/ inline weights ----
    {
        dim3 g(4, Mp / 128, 1);
        k_gemm_mfma<128, 128, false><<<g, 256, 0, stream>>>(fbuf, Wt2, hbuf,
                                                            512, 512, 512, 0, 0, 0, nullptr);
    }
    k_alpha<128, 4><<<alphaBlocks4, 256, 0, stream>>>(hbuf, as2, ad2, aS, aD, N);
    k_gather512<true><<<gatBlocks, 256, 0, stream>>>(hbuf, aS, aD, cnt, rp, col, b2, fbuf, N);

    // ---- Layer 3: GEMM (BM=64 for occupancy), alpha, gather 64ch (+b3) ----
    {
        dim3 g(1, Mp / 64, 1);
        k_gemm_mfma<64, 64, false><<<g, 256, 0, stream>>>(fbuf, Wt3, hbuf,
                                                          512, 64, 512, 0, 0, 0, nullptr);
    }
    k_alpha<64, 1><<<alphaBlocks1, 256, 0, stream>>>(hbuf, as3, ad3, aS, aD, N);
    k_gather64<<<gatBlocks, 256, 0, stream>>>(hbuf, aS, aD, cnt, rp, col, b3,
                                              (float*)d_out, N);
}

// Round 10
// 400.316 us; speedup vs baseline: 1.1788x; 1.0198x over previous
//
#include <hip/hip_runtime.h>
#include <hip/hip_bf16.h>

// ---------------------------------------------------------------------------
// 3-layer GAT (eval mode) on MI355X.
//   L1: alpha1 = X@(W1@a) ; Xagg = softmax-gather of X (128ch) ;
//       f1 = ELU(Xagg @ W1 + b1)  (per-head fused GEMM)
//   L2: h2 = f1@W2 (epilogue computes alpha2) ; full-row gather of h2 with
//       inline weights (+b2, ELU); gather epilogue computes alpha3 from f2
//   L3: h3 = f2@W3 ; gather 64ch w/ inline weights (+b3)
// ---------------------------------------------------------------------------

typedef __attribute__((ext_vector_type(8))) short bf16x8;
typedef __attribute__((ext_vector_type(4))) float f32x4;

__device__ __forceinline__ float bflo(unsigned w) { return __uint_as_float(w << 16); }
__device__ __forceinline__ float bfhi(unsigned w) { return __uint_as_float(w & 0xffff0000u); }
__device__ __forceinline__ float leaky(float x) { return x > 0.f ? x : 0.2f * x; }
__device__ __forceinline__ unsigned pack2(float a, float b) {
    unsigned ua = __bfloat16_as_ushort(__float2bfloat16(a));
    unsigned ub = __bfloat16_as_ushort(__float2bfloat16(b));
    return ua | (ub << 16);
}

// ------------------------- CSR build ---------------------------------------

__global__ void k_count(const int* __restrict__ ei, int E, int N, int* __restrict__ cnt) {
    int e = blockIdx.x * blockDim.x + threadIdx.x;
    int tot = E + N;
    if (e >= tot) return;
    int d = (e < E) ? ei[E + e] : (e - E);
    atomicAdd(&cnt[d], 1);
}

// scan of padded counts cp = (cnt+3)&~3
__global__ void k_scan1(const int* __restrict__ cnt, int N, int* __restrict__ rp,
                        int* __restrict__ blksum) {
    __shared__ int sdata[256];
    int t = threadIdx.x;
    int base = blockIdx.x * 1024;
    int v[4];
    int loc = 0;
#pragma unroll
    for (int i = 0; i < 4; i++) {
        int idx = base + t * 4 + i;
        v[i] = (idx < N) ? ((cnt[idx] + 3) & ~3) : 0;
        loc += v[i];
    }
    int x = loc;
    sdata[t] = x;
    __syncthreads();
    for (int off = 1; off < 256; off <<= 1) {
        int y = (t >= off) ? sdata[t - off] : 0;
        __syncthreads();
        x += y;
        sdata[t] = x;
        __syncthreads();
    }
    int run = x - loc;
#pragma unroll
    for (int i = 0; i < 4; i++) {
        int idx = base + t * 4 + i;
        if (idx < N) rp[idx] = run;
        run += v[i];
    }
    if (t == 255) blksum[blockIdx.x] = x;
}

__global__ void k_scan2(const int* __restrict__ blksum, int nblk, int* __restrict__ blkoff) {
    int l = threadIdx.x;
    int v = (l < nblk) ? blksum[l] : 0;
    int x = v;
#pragma unroll
    for (int off = 1; off < 64; off <<= 1) {
        int y = __shfl_up(x, off);
        if (l >= off) x += y;
    }
    if (l < nblk) blkoff[l] = x - v;
}

// finalize rp, init cur, and fill pad slots (col=0, dste=-1)
__global__ void k_scan3(int* __restrict__ rp, const int* __restrict__ blkoff,
                        const int* __restrict__ blksum, const int* __restrict__ cnt,
                        int N, int nblk, int* __restrict__ cur,
                        int* __restrict__ col, int* __restrict__ dste) {
    int i = blockIdx.x * blockDim.x + threadIdx.x;
    if (i < N) {
        int v = rp[i] + blkoff[i >> 10];
        rp[i] = v;
        cur[i] = v;
        int c = cnt[i];
        int pad = ((c + 3) & ~3) - c;
        for (int p = 0; p < pad; p++) {
            col[v + c + p] = 0;
            dste[v + c + p] = -1;
        }
    }
    if (i == 0) rp[N] = blkoff[nblk - 1] + blksum[nblk - 1];
}

__global__ void k_fill(const int* __restrict__ ei, int E, int N, int* __restrict__ cur,
                       int* __restrict__ col, int* __restrict__ dste) {
    int e = blockIdx.x * blockDim.x + threadIdx.x;
    int tot = E + N;
    if (e >= tot) return;
    int s, d;
    if (e < E) { s = ei[e]; d = ei[E + e]; }
    else       { s = e - E; d = e - E; }
    int p = atomicAdd(&cur[d], 1);
    col[p] = s;
    dste[p] = d;
}

// ------------------------- casts & small precomputes ------------------------

__global__ void k_cast_pad(const float* __restrict__ X, __hip_bfloat16* __restrict__ Xb,
                           int n_elems, int total) {
    int i = (blockIdx.x * blockDim.x + threadIdx.x) * 4;
    if (i >= total) return;
    float4 v = make_float4(0.f, 0.f, 0.f, 0.f);
    if (i < n_elems) v = *(const float4*)&X[i];
    __hip_bfloat16 tmp[4] = {__float2bfloat16(v.x), __float2bfloat16(v.y),
                             __float2bfloat16(v.z), __float2bfloat16(v.w)};
    *(ushort4*)&Xb[i] = *(const ushort4*)tmp;
}

__global__ void k_castT(const float* __restrict__ W, __hip_bfloat16* __restrict__ Wt,
                        int K, int Nw) {
    __shared__ float t[32][33];
    int k0 = blockIdx.x * 32, n0 = blockIdx.y * 32;
    int tx = threadIdx.x & 31, ty = threadIdx.x >> 5;
    for (int i = ty; i < 32; i += 8) t[i][tx] = W[(size_t)(k0 + i) * Nw + n0 + tx];
    __syncthreads();
    for (int i = ty; i < 32; i += 8)
        Wt[(size_t)(n0 + i) * K + k0 + tx] = __float2bfloat16(t[tx][i]);
}

// va8[c][0..3] = (W1[c, h*128:]·a_src[h]),  va8[c][4..7] = same with a_dst.
__global__ void k_va1(const float* __restrict__ W1, const float* __restrict__ asrc,
                      const float* __restrict__ adst, float* __restrict__ va8) {
    int t = threadIdx.x;        // 512 threads: c = t>>2, h = t&3
    int c = t >> 2, h = t & 3;
    const float* wrow = W1 + (size_t)c * 512 + h * 128;
    const float* av = asrc + h * 128;
    const float* dv = adst + h * 128;
    float vs = 0.f, vd = 0.f;
    for (int k = 0; k < 128; k++) {
        float wv = wrow[k];
        vs += wv * av[k];
        vd += wv * dv[k];
    }
    va8[c * 8 + h] = vs;
    va8[c * 8 + 4 + h] = vd;
}

// va3s[c] = W3[c,:]·a_src3 ; va3d[c] = W3[c,:]·a_dst3   (c in [0,512))
__global__ void k_va3(const float* __restrict__ W3, const float* __restrict__ asrc,
                      const float* __restrict__ adst, float* __restrict__ va3s,
                      float* __restrict__ va3d) {
    int c = threadIdx.x;  // 512 threads
    const float* wrow = W3 + (size_t)c * 64;
    float vs = 0.f, vd = 0.f;
    for (int k = 0; k < 64; k++) {
        float wv = wrow[k];
        vs += wv * asrc[k];
        vd += wv * adst[k];
    }
    va3s[c] = vs;
    va3d[c] = vd;
}

// alpha for layer 1 straight from X (bf16): one wave per node.
__global__ void k_alpha_x(const __hip_bfloat16* __restrict__ xb,
                          const float* __restrict__ va8, float* __restrict__ as_out,
                          float* __restrict__ ad_out, int N) {
    int w = (blockIdx.x * blockDim.x + threadIdx.x) >> 6;
    int lane = threadIdx.x & 63;
    if (w >= N) return;
    unsigned wrd = ((const unsigned*)xb)[(size_t)w * 64 + lane];
    float f0 = bflo(wrd), f1 = bfhi(wrd);
    int c0 = lane * 2;
    float4 vs0 = *(const float4*)&va8[c0 * 8];
    float4 vd0 = *(const float4*)&va8[c0 * 8 + 4];
    float4 vs1 = *(const float4*)&va8[(c0 + 1) * 8];
    float4 vd1 = *(const float4*)&va8[(c0 + 1) * 8 + 4];
    float s[8];
    s[0] = f0 * vs0.x + f1 * vs1.x;
    s[1] = f0 * vs0.y + f1 * vs1.y;
    s[2] = f0 * vs0.z + f1 * vs1.z;
    s[3] = f0 * vs0.w + f1 * vs1.w;
    s[4] = f0 * vd0.x + f1 * vd1.x;
    s[5] = f0 * vd0.y + f1 * vd1.y;
    s[6] = f0 * vd0.z + f1 * vd1.z;
    s[7] = f0 * vd0.w + f1 * vd1.w;
#pragma unroll
    for (int off = 32; off >= 1; off >>= 1)
#pragma unroll
        for (int j = 0; j < 8; j++) s[j] += __shfl_xor(s[j], off);
    if (lane == 0) {
        *(float4*)&as_out[w * 4] = make_float4(s[0], s[1], s[2], s[3]);
        *(float4*)&ad_out[w * 4] = make_float4(s[4], s[5], s[6], s[7]);
    }
}

// ------------------------- bf16 MFMA GEMM ----------------------------------
// C[row, cbase+col] = A[row, :K] @ Bt[col, :K]^T ; optional fused bias+ELU.
// If ALPHA (BN==128, blockIdx.x == head): epilogue also computes
// alpha_s/alpha_d[row, head] = h2[row, head*128:]·aTab[head] (no atomics:
// fr-lane shfl reduce + LDS add across the two column-half waves).

template <int BM, int BN, bool FUSE, bool ALPHA>
__global__ void __launch_bounds__(256) k_gemm_mfma(const __hip_bfloat16* __restrict__ A,
                                                   const __hip_bfloat16* __restrict__ Bt,
                                                   __hip_bfloat16* __restrict__ C,
                                                   int lda, int ldc, int K,
                                                   int hsA, int hsB, int hsC,
                                                   const float* __restrict__ bias,
                                                   const float* __restrict__ aSrcTab,
                                                   const float* __restrict__ aDstTab,
                                                   float* __restrict__ asOut,
                                                   float* __restrict__ adOut) {
    constexpr int BK = 64;
    constexpr int WM = BM / 2;
    constexpr int WN = BN / 2;
    constexpr int MREP = WM / 16;
    constexpr int NREP = WN / 16;

    __shared__ __hip_bfloat16 lds[(BM + BN) * BK];
    __hip_bfloat16* As = lds;
    __hip_bfloat16* Bs = lds + BM * BK;

    const int z = blockIdx.z;
    A += (size_t)z * hsA;
    Bt += (size_t)z * hsB;
    const int cbase = z * hsC;

    const int tid = threadIdx.x;
    const int wave = tid >> 6;
    const int lane = tid & 63;
    const int wm0 = (wave >> 1) * WM;
    const int wn0 = (wave & 1) * WN;
    const int m0 = blockIdx.y * BM;
    const int n0 = blockIdx.x * BN;
    const int fr = lane & 15;
    const int fq = lane >> 4;

    f32x4 acc[MREP][NREP] = {};

    for (int kt = 0; kt < K; kt += BK) {
        const __hip_bfloat16* srcA = A + (size_t)m0 * lda + kt;
#pragma unroll
        for (int it = 0; it < BM * 8 / 256; ++it) {
            int gb = it * 256 + wave * 64;
            int g = gb + lane;
            int row = g >> 3;
            int kg = (g & 7) ^ (row & 7);
            const __hip_bfloat16* gsrc = srcA + (size_t)row * lda + kg * 8;
            __builtin_amdgcn_global_load_lds(
                (const __attribute__((address_space(1))) void*)gsrc,
                (__attribute__((address_space(3))) void*)(As + gb * 8), 16, 0, 0);
        }
        const __hip_bfloat16* srcB = Bt + (size_t)n0 * K + kt;
#pragma unroll
        for (int it = 0; it < BN * 8 / 256; ++it) {
            int gb = it * 256 + wave * 64;
            int g = gb + lane;
            int row = g >> 3;
            int kg = (g & 7) ^ (row & 7);
            const __hip_bfloat16* gsrc = srcB + (size_t)row * K + kg * 8;
            __builtin_amdgcn_global_load_lds(
                (const __attribute__((address_space(1))) void*)gsrc,
                (__attribute__((address_space(3))) void*)(Bs + gb * 8), 16, 0, 0);
        }
        __syncthreads();

#pragma unroll
        for (int sl = 0; sl < 2; ++sl) {
            int ke = sl * 32 + fq * 8;
            bf16x8 af[MREP], bfr[NREP];
#pragma unroll
            for (int i = 0; i < MREP; ++i) {
                int row = wm0 + i * 16 + fr;
                int e = (row * BK + ke) ^ ((row & 7) << 3);
                af[i] = *(const bf16x8*)(As + e);
            }
#pragma unroll
            for (int j = 0; j < NREP; ++j) {
                int row = wn0 + j * 16 + fr;
                int e = (row * BK + ke) ^ ((row & 7) << 3);
                bfr[j] = *(const bf16x8*)(Bs + e);
            }
#pragma unroll
            for (int i = 0; i < MREP; ++i)
#pragma unroll
                for (int j = 0; j < NREP; ++j)
                    acc[i][j] = __builtin_amdgcn_mfma_f32_16x16x32_bf16(
                        af[i], bfr[j], acc[i][j], 0, 0, 0);
        }
        __syncthreads();
    }

#pragma unroll
    for (int i = 0; i < MREP; ++i) {
#pragma unroll
        for (int j = 0; j < NREP; ++j) {
            int colg = cbase + n0 + wn0 + j * 16 + fr;
#pragma unroll
            for (int r = 0; r < 4; ++r) {
                int rowg = m0 + wm0 + i * 16 + fq * 4 + r;
                float v = acc[i][j][r];
                if (FUSE) {
                    v += bias[colg];
                    v = v > 0.f ? v : expm1f(v);
                }
                C[(size_t)rowg * ldc + colg] = __float2bfloat16(v);
            }
        }
    }

    if constexpr (ALPHA) {
        const int head = blockIdx.x;
        float avs[NREP], avd[NREP];
#pragma unroll
        for (int j = 0; j < NREP; ++j) {
            int cl = wn0 + j * 16 + fr;
            avs[j] = aSrcTab[head * 128 + cl];
            avd[j] = aDstTab[head * 128 + cl];
        }
        float pa[MREP][4] = {};
        float pd_[MREP][4] = {};
#pragma unroll
        for (int i = 0; i < MREP; ++i)
#pragma unroll
            for (int j = 0; j < NREP; ++j)
#pragma unroll
                for (int r = 0; r < 4; ++r) {
                    pa[i][r] += acc[i][j][r] * avs[j];
                    pd_[i][r] += acc[i][j][r] * avd[j];
                }
        // reduce over the 16 fr lanes
#pragma unroll
        for (int off = 1; off <= 8; off <<= 1)
#pragma unroll
            for (int i = 0; i < MREP; ++i)
#pragma unroll
                for (int r = 0; r < 4; ++r) {
                    pa[i][r] += __shfl_xor(pa[i][r], off);
                    pd_[i][r] += __shfl_xor(pd_[i][r], off);
                }
        // cross-wave (column-half) add via LDS
        float* lds_a = (float*)lds;        // BM floats
        float* lds_d = lds_a + BM;         // BM floats
        if ((wave & 1) == 0 && fr == 0) {
#pragma unroll
            for (int i = 0; i < MREP; ++i)
#pragma unroll
                for (int r = 0; r < 4; ++r) {
                    int rl = wm0 + i * 16 + fq * 4 + r;
                    lds_a[rl] = pa[i][r];
                    lds_d[rl] = pd_[i][r];
                }
        }
        __syncthreads();
        if ((wave & 1) == 1 && fr == 0) {
#pragma unroll
            for (int i = 0; i < MREP; ++i)
#pragma unroll
                for (int r = 0; r < 4; ++r) {
                    int rl = wm0 + i * 16 + fq * 4 + r;
                    int rowg = m0 + rl;
                    asOut[rowg * 4 + head] = lds_a[rl] + pa[i][r];
                    adOut[rowg * 4 + head] = lds_d[rl] + pd_[i][r];
                }
        }
    }
}

// ------------------------- L1 per-edge weights (AoS) -------------------------

__global__ void k_edgewA(const int* __restrict__ col, const int* __restrict__ dste,
                         const float* __restrict__ as, const float* __restrict__ ad,
                         float* __restrict__ wA, const int* __restrict__ rp, int N) {
    int e = blockIdx.x * blockDim.x + threadIdx.x;
    if (e >= rp[N]) return;
    int d = dste[e];
    if (d < 0) {
        *(float4*)&wA[e * 4] = make_float4(0.f, 0.f, 0.f, 0.f);
        return;
    }
    int s = col[e];
    float4 a = *(const float4*)&as[s * 4];
    float4 b = *(const float4*)&ad[d * 4];
    float4 w;
    w.x = __expf(leaky(a.x + b.x));
    w.y = __expf(leaky(a.y + b.y));
    w.z = __expf(leaky(a.z + b.z));
    w.w = __expf(leaky(a.w + b.w));
    *(float4*)&wA[e * 4] = w;
}

// ------------------------- gathers ------------------------------------------
// L1: gather X rows (128 ch bf16); one wave per dst; lane owns 2 channels,
// accumulates all 4 heads. Output normalized Xagg [N][4*128] bf16.

__global__ void k_gatherX(const __hip_bfloat16* __restrict__ xb,
                          const float* __restrict__ wA, const int* __restrict__ rp,
                          const int* __restrict__ col, unsigned* __restrict__ out32, int N) {
    int w = (blockIdx.x * blockDim.x + threadIdx.x) >> 6;
    int lane = threadIdx.x & 63;
    if (w >= N) return;
    int d = w;
    int r0 = rp[d], r1 = rp[d + 1];
    const unsigned* xp = (const unsigned*)xb;

    float acc[8] = {};
    float ws0 = 0.f, ws1 = 0.f, ws2 = 0.f, ws3 = 0.f;
    for (int e = r0; e < r1; e += 4) {
        int4 c4 = *(const int4*)&col[e];
        float4 w0 = *(const float4*)&wA[e * 4];
        float4 w1 = *(const float4*)&wA[e * 4 + 4];
        float4 w2 = *(const float4*)&wA[e * 4 + 8];
        float4 w3 = *(const float4*)&wA[e * 4 + 12];
        unsigned v0 = xp[(size_t)c4.x * 64 + lane];
        unsigned v1 = xp[(size_t)c4.y * 64 + lane];
        unsigned v2 = xp[(size_t)c4.z * 64 + lane];
        unsigned v3 = xp[(size_t)c4.w * 64 + lane];
        ws0 += w0.x + w1.x + w2.x + w3.x;
        ws1 += w0.y + w1.y + w2.y + w3.y;
        ws2 += w0.z + w1.z + w2.z + w3.z;
        ws3 += w0.w + w1.w + w2.w + w3.w;
        float f0, f1;
        f0 = bflo(v0); f1 = bfhi(v0);
        acc[0] += w0.x * f0; acc[1] += w0.x * f1;
        acc[2] += w0.y * f0; acc[3] += w0.y * f1;
        acc[4] += w0.z * f0; acc[5] += w0.z * f1;
        acc[6] += w0.w * f0; acc[7] += w0.w * f1;
        f0 = bflo(v1); f1 = bfhi(v1);
        acc[0] += w1.x * f0; acc[1] += w1.x * f1;
        acc[2] += w1.y * f0; acc[3] += w1.y * f1;
        acc[4] += w1.z * f0; acc[5] += w1.z * f1;
        acc[6] += w1.w * f0; acc[7] += w1.w * f1;
        f0 = bflo(v2); f1 = bfhi(v2);
        acc[0] += w2.x * f0; acc[1] += w2.x * f1;
        acc[2] += w2.y * f0; acc[3] += w2.y * f1;
        acc[4] += w2.z * f0; acc[5] += w2.z * f1;
        acc[6] += w2.w * f0; acc[7] += w2.w * f1;
        f0 = bflo(v3); f1 = bfhi(v3);
        acc[0] += w3.x * f0; acc[1] += w3.x * f1;
        acc[2] += w3.y * f0; acc[3] += w3.y * f1;
        acc[4] += w3.z * f0; acc[5] += w3.z * f1;
        acc[6] += w3.w * f0; acc[7] += w3.w * f1;
    }
    float i0 = 1.f / (ws0 + 1e-16f), i1 = 1.f / (ws1 + 1e-16f);
    float i2 = 1.f / (ws2 + 1e-16f), i3 = 1.f / (ws3 + 1e-16f);
    size_t ob = (size_t)d * 256 + lane;
    out32[ob]       = pack2(acc[0] * i0, acc[1] * i0);
    out32[ob + 64]  = pack2(acc[2] * i1, acc[3] * i1);
    out32[ob + 128] = pack2(acc[4] * i2, acc[5] * i2);
    out32[ob + 192] = pack2(acc[6] * i3, acc[7] * i3);
}

// L2: full-row gather of h2 (512 ch), one wave per node, 16B/lane, unroll x4.
// Inline weights w = exp(leaky(as[s,hd] + ad[d,hd])); pad masked via cnt.
// Epilogue also emits alpha3[d] = f2[d,:]·va3 (full-wave reduce).

template <bool DO_ELU>
__global__ void k_gather512(const __hip_bfloat16* __restrict__ hfeat,
                            const float* __restrict__ as4, const float* __restrict__ ad4,
                            const int* __restrict__ cnt, const int* __restrict__ rp,
                            const int* __restrict__ col, const float* __restrict__ bias,
                            __hip_bfloat16* __restrict__ out,
                            const float* __restrict__ va3s, const float* __restrict__ va3d,
                            float* __restrict__ as3, float* __restrict__ ad3, int N) {
    int w = (blockIdx.x * blockDim.x + threadIdx.x) >> 6;
    int lane = threadIdx.x & 63;
    if (w >= N) return;
    int d = w;
    int r0 = rp[d], r1 = rp[d + 1];      // quad-aligned
    int r1r = r0 + cnt[d];               // real edge end
    int hd = lane >> 4;
    float adv = ad4[d * 4 + hd];
    const uint4* hp = (const uint4*)hfeat;  // 64 uint4 per 512-ch row

    float acc[8] = {};
    float wsum = 0.f;
    for (int e = r0; e < r1; e += 4) {
        int4 c4 = *(const int4*)&col[e];
        float l0 = as4[c4.x * 4 + hd] + adv;
        float l1 = as4[c4.y * 4 + hd] + adv;
        float l2 = as4[c4.z * 4 + hd] + adv;
        float l3 = as4[c4.w * 4 + hd] + adv;
        uint4 v0 = hp[(size_t)c4.x * 64 + lane];
        uint4 v1 = hp[(size_t)c4.y * 64 + lane];
        uint4 v2 = hp[(size_t)c4.z * 64 + lane];
        uint4 v3 = hp[(size_t)c4.w * 64 + lane];
        float w0 = (e + 0 < r1r) ? __expf(leaky(l0)) : 0.f;
        float w1 = (e + 1 < r1r) ? __expf(leaky(l1)) : 0.f;
        float w2 = (e + 2 < r1r) ? __expf(leaky(l2)) : 0.f;
        float w3 = (e + 3 < r1r) ? __expf(leaky(l3)) : 0.f;
        wsum += (w0 + w1) + (w2 + w3);
        acc[0] += w0 * bflo(v0.x); acc[1] += w0 * bfhi(v0.x);
        acc[2] += w0 * bflo(v0.y); acc[3] += w0 * bfhi(v0.y);
        acc[4] += w0 * bflo(v0.z); acc[5] += w0 * bfhi(v0.z);
        acc[6] += w0 * bflo(v0.w); acc[7] += w0 * bfhi(v0.w);
        acc[0] += w1 * bflo(v1.x); acc[1] += w1 * bfhi(v1.x);
        acc[2] += w1 * bflo(v1.y); acc[3] += w1 * bfhi(v1.y);
        acc[4] += w1 * bflo(v1.z); acc[5] += w1 * bfhi(v1.z);
        acc[6] += w1 * bflo(v1.w); acc[7] += w1 * bfhi(v1.w);
        acc[0] += w2 * bflo(v2.x); acc[1] += w2 * bfhi(v2.x);
        acc[2] += w2 * bflo(v2.y); acc[3] += w2 * bfhi(v2.y);
        acc[4] += w2 * bflo(v2.z); acc[5] += w2 * bfhi(v2.z);
        acc[6] += w2 * bflo(v2.w); acc[7] += w2 * bfhi(v2.w);
        acc[0] += w3 * bflo(v3.x); acc[1] += w3 * bfhi(v3.x);
        acc[2] += w3 * bflo(v3.y); acc[3] += w3 * bfhi(v3.y);
        acc[4] += w3 * bflo(v3.z); acc[5] += w3 * bfhi(v3.z);
        acc[6] += w3 * bflo(v3.w); acc[7] += w3 * bfhi(v3.w);
    }

    float inv = 1.0f / (wsum + 1e-16f);
    float vals[8];
    __hip_bfloat16 tmp[8];
#pragma unroll
    for (int j = 0; j < 8; j++) {
        float v = acc[j] * inv + bias[lane * 8 + j];
        if (DO_ELU) v = v > 0.f ? v : expm1f(v);
        vals[j] = v;
        tmp[j] = __float2bfloat16(v);
    }
    *(float4*)(out + (size_t)d * 512 + lane * 8) = *(const float4*)tmp;

    // fused alpha3 from f2 (vals)
    float s3 = 0.f, d3 = 0.f;
#pragma unroll
    for (int j = 0; j < 8; j++) {
        s3 += vals[j] * va3s[lane * 8 + j];
        d3 += vals[j] * va3d[lane * 8 + j];
    }
#pragma unroll
    for (int off = 32; off >= 1; off >>= 1) {
        s3 += __shfl_xor(s3, off);
        d3 += __shfl_xor(d3, off);
    }
    if (lane == 0) {
        as3[d] = s3;
        ad3[d] = d3;
    }
}

// L3: CT=64, H=1, f32 out: 16-lane groups each handle one edge, 4 edges/iter,
// inline weights (single head), pad masked via cnt.

__global__ void k_gather64(const __hip_bfloat16* __restrict__ hfeat,
                           const float* __restrict__ as1, const float* __restrict__ ad1,
                           const int* __restrict__ cnt, const int* __restrict__ rp,
                           const int* __restrict__ col, const float* __restrict__ bias,
                           float* __restrict__ out, int N) {
    int w = (blockIdx.x * blockDim.x + threadIdx.x) >> 6;
    int lane = threadIdx.x & 63;
    if (w >= N) return;
    int d = w;
    int r0 = rp[d], r1 = rp[d + 1];
    int r1r = r0 + cnt[d];
    float adv = ad1[d];
    int g = lane >> 4, cl = lane & 15;

    float a0 = 0.f, a1 = 0.f, a2 = 0.f, a3 = 0.f, wsum = 0.f;
    for (int e0 = r0; e0 < r1; e0 += 4) {
        int e = e0 + g;
        int s = col[e];
        float l = as1[s] + adv;
        uint2 q = *(const uint2*)(hfeat + (size_t)s * 64 + cl * 4);
        float wf = (e < r1r) ? __expf(leaky(l)) : 0.f;
        wsum += wf;
        a0 += wf * bflo(q.x);
        a1 += wf * bfhi(q.x);
        a2 += wf * bflo(q.y);
        a3 += wf * bfhi(q.y);
    }
#pragma unroll
    for (int off = 16; off <= 32; off <<= 1) {
        a0 += __shfl_xor(a0, off);
        a1 += __shfl_xor(a1, off);
        a2 += __shfl_xor(a2, off);
        a3 += __shfl_xor(a3, off);
        wsum += __shfl_xor(wsum, off);
    }
    if (g == 0) {
        float inv = 1.0f / (wsum + 1e-16f);
        float4 b4 = *(const float4*)&bias[cl * 4];
        float4 o = make_float4(a0 * inv + b4.x, a1 * inv + b4.y,
                               a2 * inv + b4.z, a3 * inv + b4.w);
        *(float4*)(out + (size_t)d * 64 + cl * 4) = o;
    }
}

// ------------------------- host launcher ------------------------------------

extern "C" void kernel_launch(void* const* d_in, const int* in_sizes, int n_in,
                              void* d_out, int out_size, void* d_ws, size_t ws_size,
                              hipStream_t stream) {
    const float* x   = (const float*)d_in[0];
    const int*   ei  = (const int*)d_in[1];
    const float* W1  = (const float*)d_in[2];
    const float* as1 = (const float*)d_in[3];
    const float* ad1 = (const float*)d_in[4];
    const float* b1  = (const float*)d_in[5];
    const float* W2  = (const float*)d_in[6];
    const float* as2 = (const float*)d_in[7];
    const float* ad2 = (const float*)d_in[8];
    const float* b2  = (const float*)d_in[9];
    const float* W3  = (const float*)d_in[10];
    const float* as3 = (const float*)d_in[11];
    const float* ad3 = (const float*)d_in[12];
    const float* b3  = (const float*)d_in[13];

    const int N = in_sizes[0] / 128;     // 50000
    const int E = in_sizes[1] / 2;       // 400000
    const int Etot = E + N;
    const int EP = (Etot + 3 * N + 255) & ~255;  // padded-edge upper bound
    const int Mp = (N + 127) & ~127;     // 50048

    char* ws = (char*)d_ws;
    size_t off = 0;
    auto alloc = [&](size_t bytes) -> void* {
        void* p = ws + off;
        off = (off + bytes + 255) & ~(size_t)255;
        return p;
    };
    __hip_bfloat16* hbuf = (__hip_bfloat16*)alloc((size_t)Mp * 512 * 2);  // h2 / h3
    __hip_bfloat16* fbuf = (__hip_bfloat16*)alloc((size_t)Mp * 512 * 2);  // f1 / f2
    __hip_bfloat16* xagg = (__hip_bfloat16*)alloc((size_t)Mp * 512 * 2);  // L1 gathered X
    __hip_bfloat16* xb   = (__hip_bfloat16*)alloc((size_t)Mp * 128 * 2);
    __hip_bfloat16* Wt1  = (__hip_bfloat16*)alloc((size_t)512 * 128 * 2);
    __hip_bfloat16* Wt2  = (__hip_bfloat16*)alloc((size_t)512 * 512 * 2);
    __hip_bfloat16* Wt3  = (__hip_bfloat16*)alloc((size_t)64 * 512 * 2);
    float* aS   = (float*)alloc((size_t)Mp * 4 * 4);
    float* aD   = (float*)alloc((size_t)Mp * 4 * 4);
    float* aS3  = (float*)alloc((size_t)Mp * 4);
    float* aD3  = (float*)alloc((size_t)Mp * 4);
    float* wbuf = (float*)alloc((size_t)EP * 4 * 4);   // AoS weights (L1 only)
    float* va8  = (float*)alloc(128 * 8 * 4);
    float* va3s = (float*)alloc(512 * 4);
    float* va3d = (float*)alloc(512 * 4);
    int* cnt  = (int*)alloc((size_t)N * 4);
    int* rp   = (int*)alloc((size_t)(N + 1) * 4);
    int* cur  = (int*)alloc((size_t)N * 4);
    int* col  = (int*)alloc((size_t)EP * 4);
    int* dste = (int*)alloc((size_t)EP * 4);
    int* blks = (int*)alloc(64 * 4);
    int* blko = (int*)alloc(64 * 4);

    // ---- CSR build (padded) ----
    hipMemsetAsync(cnt, 0, (size_t)N * 4, stream);
    int thr = 256;
    k_count<<<(Etot + thr - 1) / thr, thr, 0, stream>>>(ei, E, N, cnt);
    int nblk = (N + 1023) / 1024;
    k_scan1<<<nblk, 256, 0, stream>>>(cnt, N, rp, blks);
    k_scan2<<<1, 64, 0, stream>>>(blks, nblk, blko);
    k_scan3<<<(N + 255) / 256, 256, 0, stream>>>(rp, blko, blks, cnt, N, nblk, cur, col, dste);
    k_fill<<<(Etot + thr - 1) / thr, thr, 0, stream>>>(ei, E, N, cur, col, dste);

    // ---- one-time casts + va ----
    {
        int total = Mp * 128;
        k_cast_pad<<<(total / 4 + 255) / 256, 256, 0, stream>>>(x, xb, N * 128, total);
        dim3 g1(128 / 32, 512 / 32);
        k_castT<<<g1, 256, 0, stream>>>(W1, Wt1, 128, 512);
        dim3 g2(512 / 32, 512 / 32);
        k_castT<<<g2, 256, 0, stream>>>(W2, Wt2, 512, 512);
        dim3 g3(512 / 32, 64 / 32);
        k_castT<<<g3, 256, 0, stream>>>(W3, Wt3, 512, 64);
        k_va1<<<1, 512, 0, stream>>>(W1, as1, ad1, va8);
        k_va3<<<1, 512, 0, stream>>>(W3, as3, ad3, va3s, va3d);
    }

    int edgeBlocks = (EP + 255) / 256;
    int gatBlocks = (N + 3) / 4;

    // ---- Layer 1: alpha from X, gather X, fused per-head GEMM ----
    k_alpha_x<<<gatBlocks, 256, 0, stream>>>(xb, va8, aS, aD, N);
    k_edgewA<<<edgeBlocks, 256, 0, stream>>>(col, dste, aS, aD, wbuf, rp, N);
    k_gatherX<<<gatBlocks, 256, 0, stream>>>(xb, wbuf, rp, col, (unsigned*)xagg, N);
    {
        dim3 g(1, Mp / 128, 4);  // z = head
        k_gemm_mfma<128, 128, true, false><<<g, 256, 0, stream>>>(
            xagg, Wt1, fbuf, 512, 512, 128, 128, 128 * 128, 128, b1,
            nullptr, nullptr, nullptr, nullptr);
    }

    // ---- Layer 2: GEMM w/ fused alpha2, full-row gather w/ fused alpha3 ----
    {
        dim3 g(4, Mp / 128, 1);  // x = head (BN=128 per head)
        k_gemm_mfma<128, 128, false, true><<<g, 256, 0, stream>>>(
            fbuf, Wt2, hbuf, 512, 512, 512, 0, 0, 0, nullptr,
            as2, ad2, aS, aD);
    }
    k_gather512<true><<<gatBlocks, 256, 0, stream>>>(hbuf, aS, aD, cnt, rp, col, b2,
                                                     fbuf, va3s, va3d, aS3, aD3, N);

    // ---- Layer 3: GEMM (BM=64), gather 64ch (+b3) ----
    {
        dim3 g(1, Mp / 64, 1);
        k_gemm_mfma<64, 64, false, false><<<g, 256, 0, stream>>>(
            fbuf, Wt3, hbuf, 512, 64, 512, 0, 0, 0, nullptr,
            nullptr, nullptr, nullptr, nullptr);
    }
    k_gather64<<<gatBlocks, 256, 0, stream>>>(hbuf, aS3, aD3, cnt, rp, col, b3,
                                              (float*)d_out, N);
}

// Round 11
// 384.158 us; speedup vs baseline: 1.2284x; 1.0421x over previous
//
#include <hip/hip_runtime.h>
#include <hip/hip_bf16.h>

// ---------------------------------------------------------------------------
// 3-layer GAT (eval mode) on MI355X.
//   L1: alpha1 fused into x-cast ; Xagg = softmax-gather of X (128ch) ;
//       f1 = ELU(Xagg @ W1 + b1)  (per-head fused GEMM)
//   L2: h2 = f1@W2 (epilogue computes alpha2) ; full-row gather of h2 with
//       inline weights (+b2, ELU)
//   L3: h3 = f2@W3 (epilogue computes alpha3 = h3·a3) ; gather 64ch (+b3)
// ---------------------------------------------------------------------------

typedef __attribute__((ext_vector_type(8))) short bf16x8;
typedef __attribute__((ext_vector_type(4))) float f32x4;

__device__ __forceinline__ float bflo(unsigned w) { return __uint_as_float(w << 16); }
__device__ __forceinline__ float bfhi(unsigned w) { return __uint_as_float(w & 0xffff0000u); }
__device__ __forceinline__ float leaky(float x) { return x > 0.f ? x : 0.2f * x; }
__device__ __forceinline__ unsigned pack2(float a, float b) {
    unsigned ua = __bfloat16_as_ushort(__float2bfloat16(a));
    unsigned ub = __bfloat16_as_ushort(__float2bfloat16(b));
    return ua | (ub << 16);
}

// ------------------------- CSR build ---------------------------------------

__global__ void k_count(const int* __restrict__ ei, int E, int N, int* __restrict__ cnt) {
    int e = blockIdx.x * blockDim.x + threadIdx.x;
    int tot = E + N;
    if (e >= tot) return;
    int d = (e < E) ? ei[E + e] : (e - E);
    atomicAdd(&cnt[d], 1);
}

// scan of padded counts cp = (cnt+3)&~3
__global__ void k_scan1(const int* __restrict__ cnt, int N, int* __restrict__ rp,
                        int* __restrict__ blksum) {
    __shared__ int sdata[256];
    int t = threadIdx.x;
    int base = blockIdx.x * 1024;
    int v[4];
    int loc = 0;
#pragma unroll
    for (int i = 0; i < 4; i++) {
        int idx = base + t * 4 + i;
        v[i] = (idx < N) ? ((cnt[idx] + 3) & ~3) : 0;
        loc += v[i];
    }
    int x = loc;
    sdata[t] = x;
    __syncthreads();
    for (int off = 1; off < 256; off <<= 1) {
        int y = (t >= off) ? sdata[t - off] : 0;
        __syncthreads();
        x += y;
        sdata[t] = x;
        __syncthreads();
    }
    int run = x - loc;
#pragma unroll
    for (int i = 0; i < 4; i++) {
        int idx = base + t * 4 + i;
        if (idx < N) rp[idx] = run;
        run += v[i];
    }
    if (t == 255) blksum[blockIdx.x] = x;
}

__global__ void k_scan2(const int* __restrict__ blksum, int nblk, int* __restrict__ blkoff) {
    int l = threadIdx.x;
    int v = (l < nblk) ? blksum[l] : 0;
    int x = v;
#pragma unroll
    for (int off = 1; off < 64; off <<= 1) {
        int y = __shfl_up(x, off);
        if (l >= off) x += y;
    }
    if (l < nblk) blkoff[l] = x - v;
}

// finalize rp, init cur, and fill pad slots (col=0, dste=-1)
__global__ void k_scan3(int* __restrict__ rp, const int* __restrict__ blkoff,
                        const int* __restrict__ blksum, const int* __restrict__ cnt,
                        int N, int nblk, int* __restrict__ cur,
                        int* __restrict__ col, int* __restrict__ dste) {
    int i = blockIdx.x * blockDim.x + threadIdx.x;
    if (i < N) {
        int v = rp[i] + blkoff[i >> 10];
        rp[i] = v;
        cur[i] = v;
        int c = cnt[i];
        int pad = ((c + 3) & ~3) - c;
        for (int p = 0; p < pad; p++) {
            col[v + c + p] = 0;
            dste[v + c + p] = -1;
        }
    }
    if (i == 0) rp[N] = blkoff[nblk - 1] + blksum[nblk - 1];
}

__global__ void k_fill(const int* __restrict__ ei, int E, int N, int* __restrict__ cur,
                       int* __restrict__ col, int* __restrict__ dste) {
    int e = blockIdx.x * blockDim.x + threadIdx.x;
    int tot = E + N;
    if (e >= tot) return;
    int s, d;
    if (e < E) { s = ei[e]; d = ei[E + e]; }
    else       { s = e - E; d = e - E; }
    int p = atomicAdd(&cur[d], 1);
    col[p] = s;
    dste[p] = d;
}

// ------------------------- casts & small precomputes ------------------------

// One wave per row: cast x row (128 f32) -> xb (bf16), and compute
// alpha1_s/d[row,h] = x[row,:]·va8[:,h] from the f32 values. Pad rows zeroed.
__global__ void k_cast_alpha(const float* __restrict__ X, __hip_bfloat16* __restrict__ Xb,
                             const float* __restrict__ va8, float* __restrict__ as_out,
                             float* __restrict__ ad_out, int N, int Mp) {
    int w = (blockIdx.x * blockDim.x + threadIdx.x) >> 6;
    int lane = threadIdx.x & 63;
    if (w >= Mp) return;
    unsigned* xb32 = (unsigned*)Xb;
    if (w >= N) {
        xb32[(size_t)w * 64 + lane] = 0u;
        return;
    }
    float2 xv = *(const float2*)&X[(size_t)w * 128 + lane * 2];
    xb32[(size_t)w * 64 + lane] = pack2(xv.x, xv.y);
    int c0 = lane * 2;
    float4 vs0 = *(const float4*)&va8[c0 * 8];
    float4 vd0 = *(const float4*)&va8[c0 * 8 + 4];
    float4 vs1 = *(const float4*)&va8[(c0 + 1) * 8];
    float4 vd1 = *(const float4*)&va8[(c0 + 1) * 8 + 4];
    float s[8];
    s[0] = xv.x * vs0.x + xv.y * vs1.x;
    s[1] = xv.x * vs0.y + xv.y * vs1.y;
    s[2] = xv.x * vs0.z + xv.y * vs1.z;
    s[3] = xv.x * vs0.w + xv.y * vs1.w;
    s[4] = xv.x * vd0.x + xv.y * vd1.x;
    s[5] = xv.x * vd0.y + xv.y * vd1.y;
    s[6] = xv.x * vd0.z + xv.y * vd1.z;
    s[7] = xv.x * vd0.w + xv.y * vd1.w;
#pragma unroll
    for (int off = 32; off >= 1; off >>= 1)
#pragma unroll
        for (int j = 0; j < 8; j++) s[j] += __shfl_xor(s[j], off);
    if (lane == 0) {
        *(float4*)&as_out[w * 4] = make_float4(s[0], s[1], s[2], s[3]);
        *(float4*)&ad_out[w * 4] = make_float4(s[4], s[5], s[6], s[7]);
    }
}

__global__ void k_castT(const float* __restrict__ W, __hip_bfloat16* __restrict__ Wt,
                        int K, int Nw) {
    __shared__ float t[32][33];
    int k0 = blockIdx.x * 32, n0 = blockIdx.y * 32;
    int tx = threadIdx.x & 31, ty = threadIdx.x >> 5;
    for (int i = ty; i < 32; i += 8) t[i][tx] = W[(size_t)(k0 + i) * Nw + n0 + tx];
    __syncthreads();
    for (int i = ty; i < 32; i += 8)
        Wt[(size_t)(n0 + i) * K + k0 + tx] = __float2bfloat16(t[tx][i]);
}

// va8[c][0..3] = (W1[c, h*128:]·a_src[h]),  va8[c][4..7] = same with a_dst.
__global__ void k_va1(const float* __restrict__ W1, const float* __restrict__ asrc,
                      const float* __restrict__ adst, float* __restrict__ va8) {
    int t = threadIdx.x;        // 512 threads: c = t>>2, h = t&3
    int c = t >> 2, h = t & 3;
    const float* wrow = W1 + (size_t)c * 512 + h * 128;
    const float* av = asrc + h * 128;
    const float* dv = adst + h * 128;
    float vs = 0.f, vd = 0.f;
    for (int k = 0; k < 128; k++) {
        float wv = wrow[k];
        vs += wv * av[k];
        vd += wv * dv[k];
    }
    va8[c * 8 + h] = vs;
    va8[c * 8 + 4 + h] = vd;
}

// ------------------------- bf16 MFMA GEMM ----------------------------------
// C[row, cbase+col] = A[row, :K] @ Bt[col, :K]^T ; optional fused bias+ELU.
// ALPHA_H = 0: none.  ALPHA_H = 4: (BN=128, blockIdx.x==head) epilogue emits
// alpha[row*4+head] = C_block[row,:]·aTab[head].  ALPHA_H = 1: (BN=64) emits
// alpha[row] = C_block[row,:]·aTab.  Reduce: fr-lane shfl + LDS cross-wave.

template <int BM, int BN, bool FUSE, int ALPHA_H>
__global__ void __launch_bounds__(256) k_gemm_mfma(const __hip_bfloat16* __restrict__ A,
                                                   const __hip_bfloat16* __restrict__ Bt,
                                                   __hip_bfloat16* __restrict__ C,
                                                   int lda, int ldc, int K,
                                                   int hsA, int hsB, int hsC,
                                                   const float* __restrict__ bias,
                                                   const float* __restrict__ aSrcTab,
                                                   const float* __restrict__ aDstTab,
                                                   float* __restrict__ asOut,
                                                   float* __restrict__ adOut) {
    constexpr int BK = 64;
    constexpr int WM = BM / 2;
    constexpr int WN = BN / 2;
    constexpr int MREP = WM / 16;
    constexpr int NREP = WN / 16;

    __shared__ __hip_bfloat16 lds[(BM + BN) * BK];
    __hip_bfloat16* As = lds;
    __hip_bfloat16* Bs = lds + BM * BK;

    const int z = blockIdx.z;
    A += (size_t)z * hsA;
    Bt += (size_t)z * hsB;
    const int cbase = z * hsC;

    const int tid = threadIdx.x;
    const int wave = tid >> 6;
    const int lane = tid & 63;
    const int wm0 = (wave >> 1) * WM;
    const int wn0 = (wave & 1) * WN;
    const int m0 = blockIdx.y * BM;
    const int n0 = blockIdx.x * BN;
    const int fr = lane & 15;
    const int fq = lane >> 4;

    f32x4 acc[MREP][NREP] = {};

    for (int kt = 0; kt < K; kt += BK) {
        const __hip_bfloat16* srcA = A + (size_t)m0 * lda + kt;
#pragma unroll
        for (int it = 0; it < BM * 8 / 256; ++it) {
            int gb = it * 256 + wave * 64;
            int g = gb + lane;
            int row = g >> 3;
            int kg = (g & 7) ^ (row & 7);
            const __hip_bfloat16* gsrc = srcA + (size_t)row * lda + kg * 8;
            __builtin_amdgcn_global_load_lds(
                (const __attribute__((address_space(1))) void*)gsrc,
                (__attribute__((address_space(3))) void*)(As + gb * 8), 16, 0, 0);
        }
        const __hip_bfloat16* srcB = Bt + (size_t)n0 * K + kt;
#pragma unroll
        for (int it = 0; it < BN * 8 / 256; ++it) {
            int gb = it * 256 + wave * 64;
            int g = gb + lane;
            int row = g >> 3;
            int kg = (g & 7) ^ (row & 7);
            const __hip_bfloat16* gsrc = srcB + (size_t)row * K + kg * 8;
            __builtin_amdgcn_global_load_lds(
                (const __attribute__((address_space(1))) void*)gsrc,
                (__attribute__((address_space(3))) void*)(Bs + gb * 8), 16, 0, 0);
        }
        __syncthreads();

#pragma unroll
        for (int sl = 0; sl < 2; ++sl) {
            int ke = sl * 32 + fq * 8;
            bf16x8 af[MREP], bfr[NREP];
#pragma unroll
            for (int i = 0; i < MREP; ++i) {
                int row = wm0 + i * 16 + fr;
                int e = (row * BK + ke) ^ ((row & 7) << 3);
                af[i] = *(const bf16x8*)(As + e);
            }
#pragma unroll
            for (int j = 0; j < NREP; ++j) {
                int row = wn0 + j * 16 + fr;
                int e = (row * BK + ke) ^ ((row & 7) << 3);
                bfr[j] = *(const bf16x8*)(Bs + e);
            }
#pragma unroll
            for (int i = 0; i < MREP; ++i)
#pragma unroll
                for (int j = 0; j < NREP; ++j)
                    acc[i][j] = __builtin_amdgcn_mfma_f32_16x16x32_bf16(
                        af[i], bfr[j], acc[i][j], 0, 0, 0);
        }
        __syncthreads();
    }

#pragma unroll
    for (int i = 0; i < MREP; ++i) {
#pragma unroll
        for (int j = 0; j < NREP; ++j) {
            int colg = cbase + n0 + wn0 + j * 16 + fr;
#pragma unroll
            for (int r = 0; r < 4; ++r) {
                int rowg = m0 + wm0 + i * 16 + fq * 4 + r;
                float v = acc[i][j][r];
                if (FUSE) {
                    v += bias[colg];
                    v = v > 0.f ? v : expm1f(v);
                }
                C[(size_t)rowg * ldc + colg] = __float2bfloat16(v);
            }
        }
    }

    if constexpr (ALPHA_H > 0) {
        const int head = (ALPHA_H == 4) ? blockIdx.x : 0;
        float avs[NREP], avd[NREP];
#pragma unroll
        for (int j = 0; j < NREP; ++j) {
            int cl = wn0 + j * 16 + fr;
            avs[j] = aSrcTab[head * BN + cl];
            avd[j] = aDstTab[head * BN + cl];
        }
        float pa[MREP][4] = {};
        float pd_[MREP][4] = {};
#pragma unroll
        for (int i = 0; i < MREP; ++i)
#pragma unroll
            for (int j = 0; j < NREP; ++j)
#pragma unroll
                for (int r = 0; r < 4; ++r) {
                    pa[i][r] += acc[i][j][r] * avs[j];
                    pd_[i][r] += acc[i][j][r] * avd[j];
                }
        // reduce over the 16 fr lanes
#pragma unroll
        for (int off = 1; off <= 8; off <<= 1)
#pragma unroll
            for (int i = 0; i < MREP; ++i)
#pragma unroll
                for (int r = 0; r < 4; ++r) {
                    pa[i][r] += __shfl_xor(pa[i][r], off);
                    pd_[i][r] += __shfl_xor(pd_[i][r], off);
                }
        // cross-wave (column-half) add via LDS
        float* lds_a = (float*)lds;        // BM floats
        float* lds_d = lds_a + BM;         // BM floats
        if ((wave & 1) == 0 && fr == 0) {
#pragma unroll
            for (int i = 0; i < MREP; ++i)
#pragma unroll
                for (int r = 0; r < 4; ++r) {
                    int rl = wm0 + i * 16 + fq * 4 + r;
                    lds_a[rl] = pa[i][r];
                    lds_d[rl] = pd_[i][r];
                }
        }
        __syncthreads();
        if ((wave & 1) == 1 && fr == 0) {
#pragma unroll
            for (int i = 0; i < MREP; ++i)
#pragma unroll
                for (int r = 0; r < 4; ++r) {
                    int rl = wm0 + i * 16 + fq * 4 + r;
                    int rowg = m0 + rl;
                    if (ALPHA_H == 4) {
                        asOut[rowg * 4 + head] = lds_a[rl] + pa[i][r];
                        adOut[rowg * 4 + head] = lds_d[rl] + pd_[i][r];
                    } else {
                        asOut[rowg] = lds_a[rl] + pa[i][r];
                        adOut[rowg] = lds_d[rl] + pd_[i][r];
                    }
                }
        }
    }
}

// ------------------------- L1 per-edge weights (AoS) -------------------------

__global__ void k_edgewA(const int* __restrict__ col, const int* __restrict__ dste,
                         const float* __restrict__ as, const float* __restrict__ ad,
                         float* __restrict__ wA, const int* __restrict__ rp, int N) {
    int e = blockIdx.x * blockDim.x + threadIdx.x;
    if (e >= rp[N]) return;
    int d = dste[e];
    if (d < 0) {
        *(float4*)&wA[e * 4] = make_float4(0.f, 0.f, 0.f, 0.f);
        return;
    }
    int s = col[e];
    float4 a = *(const float4*)&as[s * 4];
    float4 b = *(const float4*)&ad[d * 4];
    float4 w;
    w.x = __expf(leaky(a.x + b.x));
    w.y = __expf(leaky(a.y + b.y));
    w.z = __expf(leaky(a.z + b.z));
    w.w = __expf(leaky(a.w + b.w));
    *(float4*)&wA[e * 4] = w;
}

// ------------------------- gathers ------------------------------------------
// L1: gather X rows (128 ch bf16); one wave per dst; lane owns 2 channels,
// accumulates all 4 heads. Output normalized Xagg [N][4*128] bf16.

__global__ void k_gatherX(const __hip_bfloat16* __restrict__ xb,
                          const float* __restrict__ wA, const int* __restrict__ rp,
                          const int* __restrict__ col, unsigned* __restrict__ out32, int N) {
    int w = (blockIdx.x * blockDim.x + threadIdx.x) >> 6;
    int lane = threadIdx.x & 63;
    if (w >= N) return;
    int d = w;
    int r0 = rp[d], r1 = rp[d + 1];
    const unsigned* xp = (const unsigned*)xb;

    float acc[8] = {};
    float ws0 = 0.f, ws1 = 0.f, ws2 = 0.f, ws3 = 0.f;
    for (int e = r0; e < r1; e += 4) {
        int4 c4 = *(const int4*)&col[e];
        float4 w0 = *(const float4*)&wA[e * 4];
        float4 w1 = *(const float4*)&wA[e * 4 + 4];
        float4 w2 = *(const float4*)&wA[e * 4 + 8];
        float4 w3 = *(const float4*)&wA[e * 4 + 12];
        unsigned v0 = xp[(size_t)c4.x * 64 + lane];
        unsigned v1 = xp[(size_t)c4.y * 64 + lane];
        unsigned v2 = xp[(size_t)c4.z * 64 + lane];
        unsigned v3 = xp[(size_t)c4.w * 64 + lane];
        ws0 += w0.x + w1.x + w2.x + w3.x;
        ws1 += w0.y + w1.y + w2.y + w3.y;
        ws2 += w0.z + w1.z + w2.z + w3.z;
        ws3 += w0.w + w1.w + w2.w + w3.w;
        float f0, f1;
        f0 = bflo(v0); f1 = bfhi(v0);
        acc[0] += w0.x * f0; acc[1] += w0.x * f1;
        acc[2] += w0.y * f0; acc[3] += w0.y * f1;
        acc[4] += w0.z * f0; acc[5] += w0.z * f1;
        acc[6] += w0.w * f0; acc[7] += w0.w * f1;
        f0 = bflo(v1); f1 = bfhi(v1);
        acc[0] += w1.x * f0; acc[1] += w1.x * f1;
        acc[2] += w1.y * f0; acc[3] += w1.y * f1;
        acc[4] += w1.z * f0; acc[5] += w1.z * f1;
        acc[6] += w1.w * f0; acc[7] += w1.w * f1;
        f0 = bflo(v2); f1 = bfhi(v2);
        acc[0] += w2.x * f0; acc[1] += w2.x * f1;
        acc[2] += w2.y * f0; acc[3] += w2.y * f1;
        acc[4] += w2.z * f0; acc[5] += w2.z * f1;
        acc[6] += w2.w * f0; acc[7] += w2.w * f1;
        f0 = bflo(v3); f1 = bfhi(v3);
        acc[0] += w3.x * f0; acc[1] += w3.x * f1;
        acc[2] += w3.y * f0; acc[3] += w3.y * f1;
        acc[4] += w3.z * f0; acc[5] += w3.z * f1;
        acc[6] += w3.w * f0; acc[7] += w3.w * f1;
    }
    float i0 = 1.f / (ws0 + 1e-16f), i1 = 1.f / (ws1 + 1e-16f);
    float i2 = 1.f / (ws2 + 1e-16f), i3 = 1.f / (ws3 + 1e-16f);
    size_t ob = (size_t)d * 256 + lane;
    out32[ob]       = pack2(acc[0] * i0, acc[1] * i0);
    out32[ob + 64]  = pack2(acc[2] * i1, acc[3] * i1);
    out32[ob + 128] = pack2(acc[4] * i2, acc[5] * i2);
    out32[ob + 192] = pack2(acc[6] * i3, acc[7] * i3);
}

// L2: full-row gather of h2 (512 ch), one wave per node, 16B/lane, unroll x4.
// Inline weights w = exp(leaky(as[s,hd] + ad[d,hd])); pad masked via cnt.

template <bool DO_ELU>
__global__ void k_gather512(const __hip_bfloat16* __restrict__ hfeat,
                            const float* __restrict__ as4, const float* __restrict__ ad4,
                            const int* __restrict__ cnt, const int* __restrict__ rp,
                            const int* __restrict__ col, const float* __restrict__ bias,
                            __hip_bfloat16* __restrict__ out, int N) {
    int w = (blockIdx.x * blockDim.x + threadIdx.x) >> 6;
    int lane = threadIdx.x & 63;
    if (w >= N) return;
    int d = w;
    int r0 = rp[d], r1 = rp[d + 1];      // quad-aligned
    int r1r = r0 + cnt[d];               // real edge end
    int hd = lane >> 4;
    float adv = ad4[d * 4 + hd];
    const uint4* hp = (const uint4*)hfeat;  // 64 uint4 per 512-ch row

    float acc[8] = {};
    float wsum = 0.f;
    for (int e = r0; e < r1; e += 4) {
        int4 c4 = *(const int4*)&col[e];
        float l0 = as4[c4.x * 4 + hd] + adv;
        float l1 = as4[c4.y * 4 + hd] + adv;
        float l2 = as4[c4.z * 4 + hd] + adv;
        float l3 = as4[c4.w * 4 + hd] + adv;
        uint4 v0 = hp[(size_t)c4.x * 64 + lane];
        uint4 v1 = hp[(size_t)c4.y * 64 + lane];
        uint4 v2 = hp[(size_t)c4.z * 64 + lane];
        uint4 v3 = hp[(size_t)c4.w * 64 + lane];
        float w0 = (e + 0 < r1r) ? __expf(leaky(l0)) : 0.f;
        float w1 = (e + 1 < r1r) ? __expf(leaky(l1)) : 0.f;
        float w2 = (e + 2 < r1r) ? __expf(leaky(l2)) : 0.f;
        float w3 = (e + 3 < r1r) ? __expf(leaky(l3)) : 0.f;
        wsum += (w0 + w1) + (w2 + w3);
        acc[0] += w0 * bflo(v0.x); acc[1] += w0 * bfhi(v0.x);
        acc[2] += w0 * bflo(v0.y); acc[3] += w0 * bfhi(v0.y);
        acc[4] += w0 * bflo(v0.z); acc[5] += w0 * bfhi(v0.z);
        acc[6] += w0 * bflo(v0.w); acc[7] += w0 * bfhi(v0.w);
        acc[0] += w1 * bflo(v1.x); acc[1] += w1 * bfhi(v1.x);
        acc[2] += w1 * bflo(v1.y); acc[3] += w1 * bfhi(v1.y);
        acc[4] += w1 * bflo(v1.z); acc[5] += w1 * bfhi(v1.z);
        acc[6] += w1 * bflo(v1.w); acc[7] += w1 * bfhi(v1.w);
        acc[0] += w2 * bflo(v2.x); acc[1] += w2 * bfhi(v2.x);
        acc[2] += w2 * bflo(v2.y); acc[3] += w2 * bfhi(v2.y);
        acc[4] += w2 * bflo(v2.z); acc[5] += w2 * bfhi(v2.z);
        acc[6] += w2 * bflo(v2.w); acc[7] += w2 * bfhi(v2.w);
        acc[0] += w3 * bflo(v3.x); acc[1] += w3 * bfhi(v3.x);
        acc[2] += w3 * bflo(v3.y); acc[3] += w3 * bfhi(v3.y);
        acc[4] += w3 * bflo(v3.z); acc[5] += w3 * bfhi(v3.z);
        acc[6] += w3 * bflo(v3.w); acc[7] += w3 * bfhi(v3.w);
    }

    float inv = 1.0f / (wsum + 1e-16f);
    __hip_bfloat16 tmp[8];
#pragma unroll
    for (int j = 0; j < 8; j++) {
        float v = acc[j] * inv + bias[lane * 8 + j];
        if (DO_ELU) v = v > 0.f ? v : expm1f(v);
        tmp[j] = __float2bfloat16(v);
    }
    *(float4*)(out + (size_t)d * 512 + lane * 8) = *(const float4*)tmp;
}

// L3: CT=64, H=1, f32 out: 16-lane groups each handle one edge, 4 edges/iter,
// inline weights (single head), pad masked via cnt.

__global__ void k_gather64(const __hip_bfloat16* __restrict__ hfeat,
                           const float* __restrict__ as1, const float* __restrict__ ad1,
                           const int* __restrict__ cnt, const int* __restrict__ rp,
                           const int* __restrict__ col, const float* __restrict__ bias,
                           float* __restrict__ out, int N) {
    int w = (blockIdx.x * blockDim.x + threadIdx.x) >> 6;
    int lane = threadIdx.x & 63;
    if (w >= N) return;
    int d = w;
    int r0 = rp[d], r1 = rp[d + 1];
    int r1r = r0 + cnt[d];
    float adv = ad1[d];
    int g = lane >> 4, cl = lane & 15;

    float a0 = 0.f, a1 = 0.f, a2 = 0.f, a3 = 0.f, wsum = 0.f;
    for (int e0 = r0; e0 < r1; e0 += 4) {
        int e = e0 + g;
        int s = col[e];
        float l = as1[s] + adv;
        uint2 q = *(const uint2*)(hfeat + (size_t)s * 64 + cl * 4);
        float wf = (e < r1r) ? __expf(leaky(l)) : 0.f;
        wsum += wf;
        a0 += wf * bflo(q.x);
        a1 += wf * bfhi(q.x);
        a2 += wf * bflo(q.y);
        a3 += wf * bfhi(q.y);
    }
#pragma unroll
    for (int off = 16; off <= 32; off <<= 1) {
        a0 += __shfl_xor(a0, off);
        a1 += __shfl_xor(a1, off);
        a2 += __shfl_xor(a2, off);
        a3 += __shfl_xor(a3, off);
        wsum += __shfl_xor(wsum, off);
    }
    if (g == 0) {
        float inv = 1.0f / (wsum + 1e-16f);
        float4 b4 = *(const float4*)&bias[cl * 4];
        float4 o = make_float4(a0 * inv + b4.x, a1 * inv + b4.y,
                               a2 * inv + b4.z, a3 * inv + b4.w);
        *(float4*)(out + (size_t)d * 64 + cl * 4) = o;
    }
}

// ------------------------- host launcher ------------------------------------

extern "C" void kernel_launch(void* const* d_in, const int* in_sizes, int n_in,
                              void* d_out, int out_size, void* d_ws, size_t ws_size,
                              hipStream_t stream) {
    const float* x   = (const float*)d_in[0];
    const int*   ei  = (const int*)d_in[1];
    const float* W1  = (const float*)d_in[2];
    const float* as1 = (const float*)d_in[3];
    const float* ad1 = (const float*)d_in[4];
    const float* b1  = (const float*)d_in[5];
    const float* W2  = (const float*)d_in[6];
    const float* as2 = (const float*)d_in[7];
    const float* ad2 = (const float*)d_in[8];
    const float* b2  = (const float*)d_in[9];
    const float* W3  = (const float*)d_in[10];
    const float* as3 = (const float*)d_in[11];
    const float* ad3 = (const float*)d_in[12];
    const float* b3  = (const float*)d_in[13];

    const int N = in_sizes[0] / 128;     // 50000
    const int E = in_sizes[1] / 2;       // 400000
    const int Etot = E + N;
    const int EP = (Etot + 3 * N + 255) & ~255;  // padded-edge upper bound
    const int Mp = (N + 127) & ~127;     // 50048

    char* ws = (char*)d_ws;
    size_t off = 0;
    auto alloc = [&](size_t bytes) -> void* {
        void* p = ws + off;
        off = (off + bytes + 255) & ~(size_t)255;
        return p;
    };
    __hip_bfloat16* hbuf = (__hip_bfloat16*)alloc((size_t)Mp * 512 * 2);  // h2 / h3
    __hip_bfloat16* fbuf = (__hip_bfloat16*)alloc((size_t)Mp * 512 * 2);  // f1 / f2
    __hip_bfloat16* xagg = (__hip_bfloat16*)alloc((size_t)Mp * 512 * 2);  // L1 gathered X
    __hip_bfloat16* xb   = (__hip_bfloat16*)alloc((size_t)Mp * 128 * 2);
    __hip_bfloat16* Wt1  = (__hip_bfloat16*)alloc((size_t)512 * 128 * 2);
    __hip_bfloat16* Wt2  = (__hip_bfloat16*)alloc((size_t)512 * 512 * 2);
    __hip_bfloat16* Wt3  = (__hip_bfloat16*)alloc((size_t)64 * 512 * 2);
    float* aS   = (float*)alloc((size_t)Mp * 4 * 4);
    float* aD   = (float*)alloc((size_t)Mp * 4 * 4);
    float* aS3  = (float*)alloc((size_t)Mp * 4);
    float* aD3  = (float*)alloc((size_t)Mp * 4);
    float* wbuf = (float*)alloc((size_t)EP * 4 * 4);   // AoS weights (L1 only)
    float* va8  = (float*)alloc(128 * 8 * 4);
    int* cnt  = (int*)alloc((size_t)N * 4);
    int* rp   = (int*)alloc((size_t)(N + 1) * 4);
    int* cur  = (int*)alloc((size_t)N * 4);
    int* col  = (int*)alloc((size_t)EP * 4);
    int* dste = (int*)alloc((size_t)EP * 4);
    int* blks = (int*)alloc(64 * 4);
    int* blko = (int*)alloc(64 * 4);

    // ---- CSR build (padded) ----
    hipMemsetAsync(cnt, 0, (size_t)N * 4, stream);
    int thr = 256;
    k_count<<<(Etot + thr - 1) / thr, thr, 0, stream>>>(ei, E, N, cnt);
    int nblk = (N + 1023) / 1024;
    k_scan1<<<nblk, 256, 0, stream>>>(cnt, N, rp, blks);
    k_scan2<<<1, 64, 0, stream>>>(blks, nblk, blko);
    k_scan3<<<(N + 255) / 256, 256, 0, stream>>>(rp, blko, blks, cnt, N, nblk, cur, col, dste);
    k_fill<<<(Etot + thr - 1) / thr, thr, 0, stream>>>(ei, E, N, cur, col, dste);

    // ---- one-time casts + va + fused alpha1 ----
    {
        dim3 g1(128 / 32, 512 / 32);
        k_castT<<<g1, 256, 0, stream>>>(W1, Wt1, 128, 512);
        dim3 g2(512 / 32, 512 / 32);
        k_castT<<<g2, 256, 0, stream>>>(W2, Wt2, 512, 512);
        dim3 g3(512 / 32, 64 / 32);
        k_castT<<<g3, 256, 0, stream>>>(W3, Wt3, 512, 64);
        k_va1<<<1, 512, 0, stream>>>(W1, as1, ad1, va8);
        k_cast_alpha<<<(Mp + 3) / 4, 256, 0, stream>>>(x, xb, va8, aS, aD, N, Mp);
    }

    int edgeBlocks = (EP + 255) / 256;
    int gatBlocks = (N + 3) / 4;

    // ---- Layer 1: edge weights, gather X, fused per-head GEMM ----
    k_edgewA<<<edgeBlocks, 256, 0, stream>>>(col, dste, aS, aD, wbuf, rp, N);
    k_gatherX<<<gatBlocks, 256, 0, stream>>>(xb, wbuf, rp, col, (unsigned*)xagg, N);
    {
        dim3 g(1, Mp / 128, 4);  // z = head
        k_gemm_mfma<128, 128, true, 0><<<g, 256, 0, stream>>>(
            xagg, Wt1, fbuf, 512, 512, 128, 128, 128 * 128, 128, b1,
            nullptr, nullptr, nullptr, nullptr);
    }

    // ---- Layer 2: GEMM w/ fused alpha2, full-row gather (+b2, ELU) ----
    {
        dim3 g(4, Mp / 128, 1);  // x = head (BN=128 per head)
        k_gemm_mfma<128, 128, false, 4><<<g, 256, 0, stream>>>(
            fbuf, Wt2, hbuf, 512, 512, 512, 0, 0, 0, nullptr,
            as2, ad2, aS, aD);
    }
    k_gather512<true><<<gatBlocks, 256, 0, stream>>>(hbuf, aS, aD, cnt, rp, col, b2,
                                                     fbuf, N);

    // ---- Layer 3: GEMM (BM=64) w/ fused alpha3, gather 64ch (+b3) ----
    {
        dim3 g(1, Mp / 64, 1);
        k_gemm_mfma<64, 64, false, 1><<<g, 256, 0, stream>>>(
            fbuf, Wt3, hbuf, 512, 64, 512, 0, 0, 0, nullptr,
            as3, ad3, aS3, aD3);
    }
    k_gather64<<<gatBlocks, 256, 0, stream>>>(hbuf, aS3, aD3, cnt, rp, col, b3,
                                              (float*)d_out, N);
}

// Round 12
// 377.647 us; speedup vs baseline: 1.2495x; 1.0172x over previous
//
#include <hip/hip_runtime.h>
#include <hip/hip_bf16.h>

// ---------------------------------------------------------------------------
// 3-layer GAT (eval mode) on MI355X.
//   L1: alpha1 fused into x-cast ; Xagg = softmax-gather of X (128ch, inline
//       cooperative edge weights) ; f1 = ELU(Xagg @ W1 + b1) (per-head GEMM)
//   L2: h2 = f1@W2 (epilogue computes alpha2) ; full-row gather of h2 with
//       inline weights (+b2, ELU)
//   L3: h3 = f2@W3 (epilogue computes alpha3 = h3·a3) ; gather 64ch (+b3)
// ---------------------------------------------------------------------------

typedef __attribute__((ext_vector_type(8))) short bf16x8;
typedef __attribute__((ext_vector_type(4))) float f32x4;

__device__ __forceinline__ float bflo(unsigned w) { return __uint_as_float(w << 16); }
__device__ __forceinline__ float bfhi(unsigned w) { return __uint_as_float(w & 0xffff0000u); }
__device__ __forceinline__ float leaky(float x) { return x > 0.f ? x : 0.2f * x; }
__device__ __forceinline__ unsigned pack2(float a, float b) {
    unsigned ua = __bfloat16_as_ushort(__float2bfloat16(a));
    unsigned ub = __bfloat16_as_ushort(__float2bfloat16(b));
    return ua | (ub << 16);
}

// ------------------------- CSR build ---------------------------------------

__global__ void k_count(const int* __restrict__ ei, int E, int N, int* __restrict__ cnt) {
    int e = blockIdx.x * blockDim.x + threadIdx.x;
    int tot = E + N;
    if (e >= tot) return;
    int d = (e < E) ? ei[E + e] : (e - E);
    atomicAdd(&cnt[d], 1);
}

// scan of padded counts cp = (cnt+3)&~3
__global__ void k_scan1(const int* __restrict__ cnt, int N, int* __restrict__ rp,
                        int* __restrict__ blksum) {
    __shared__ int sdata[256];
    int t = threadIdx.x;
    int base = blockIdx.x * 1024;
    int v[4];
    int loc = 0;
#pragma unroll
    for (int i = 0; i < 4; i++) {
        int idx = base + t * 4 + i;
        v[i] = (idx < N) ? ((cnt[idx] + 3) & ~3) : 0;
        loc += v[i];
    }
    int x = loc;
    sdata[t] = x;
    __syncthreads();
    for (int off = 1; off < 256; off <<= 1) {
        int y = (t >= off) ? sdata[t - off] : 0;
        __syncthreads();
        x += y;
        sdata[t] = x;
        __syncthreads();
    }
    int run = x - loc;
#pragma unroll
    for (int i = 0; i < 4; i++) {
        int idx = base + t * 4 + i;
        if (idx < N) rp[idx] = run;
        run += v[i];
    }
    if (t == 255) blksum[blockIdx.x] = x;
}

// finalize rp (adds block prefix computed in-wave from blksum), init cur,
// fill pad cols. nblk <= 64.
__global__ void k_scan3(int* __restrict__ rp, const int* __restrict__ blksum,
                        const int* __restrict__ cnt, int N, int nblk,
                        int* __restrict__ cur, int* __restrict__ col) {
    __shared__ int lblk[64];
    if (threadIdx.x < 64) {
        int l = threadIdx.x;
        int v = (l < nblk) ? blksum[l] : 0;
        int x = v;
#pragma unroll
        for (int off = 1; off < 64; off <<= 1) {
            int y = __shfl_up(x, off);
            if (l >= off) x += y;
        }
        lblk[l] = x - v;  // exclusive prefix
    }
    __syncthreads();
    int i = blockIdx.x * blockDim.x + threadIdx.x;
    if (i < N) {
        int v = rp[i] + lblk[i >> 10];
        rp[i] = v;
        cur[i] = v;
        int c = cnt[i];
        int pad = ((c + 3) & ~3) - c;
        for (int p = 0; p < pad; p++) col[v + c + p] = 0;
    }
    if (i == 0) rp[N] = lblk[nblk - 1] + blksum[nblk - 1];
}

__global__ void k_fill(const int* __restrict__ ei, int E, int N, int* __restrict__ cur,
                       int* __restrict__ col) {
    int e = blockIdx.x * blockDim.x + threadIdx.x;
    int tot = E + N;
    if (e >= tot) return;
    int s, d;
    if (e < E) { s = ei[e]; d = ei[E + e]; }
    else       { s = e - E; d = e - E; }
    int p = atomicAdd(&cur[d], 1);
    col[p] = s;
}

// ------------------------- casts & small precomputes ------------------------

// One wave per row: cast x row (128 f32) -> xb (bf16), and compute
// alpha1_s/d[row,h] = x[row,:]·va8[:,h] from the f32 values. Pad rows zeroed.
__global__ void k_cast_alpha(const float* __restrict__ X, __hip_bfloat16* __restrict__ Xb,
                             const float* __restrict__ va8, float* __restrict__ as_out,
                             float* __restrict__ ad_out, int N, int Mp) {
    int w = (blockIdx.x * blockDim.x + threadIdx.x) >> 6;
    int lane = threadIdx.x & 63;
    if (w >= Mp) return;
    unsigned* xb32 = (unsigned*)Xb;
    if (w >= N) {
        xb32[(size_t)w * 64 + lane] = 0u;
        return;
    }
    float2 xv = *(const float2*)&X[(size_t)w * 128 + lane * 2];
    xb32[(size_t)w * 64 + lane] = pack2(xv.x, xv.y);
    int c0 = lane * 2;
    float4 vs0 = *(const float4*)&va8[c0 * 8];
    float4 vd0 = *(const float4*)&va8[c0 * 8 + 4];
    float4 vs1 = *(const float4*)&va8[(c0 + 1) * 8];
    float4 vd1 = *(const float4*)&va8[(c0 + 1) * 8 + 4];
    float s[8];
    s[0] = xv.x * vs0.x + xv.y * vs1.x;
    s[1] = xv.x * vs0.y + xv.y * vs1.y;
    s[2] = xv.x * vs0.z + xv.y * vs1.z;
    s[3] = xv.x * vs0.w + xv.y * vs1.w;
    s[4] = xv.x * vd0.x + xv.y * vd1.x;
    s[5] = xv.x * vd0.y + xv.y * vd1.y;
    s[6] = xv.x * vd0.z + xv.y * vd1.z;
    s[7] = xv.x * vd0.w + xv.y * vd1.w;
#pragma unroll
    for (int off = 32; off >= 1; off >>= 1)
#pragma unroll
        for (int j = 0; j < 8; j++) s[j] += __shfl_xor(s[j], off);
    if (lane == 0) {
        *(float4*)&as_out[w * 4] = make_float4(s[0], s[1], s[2], s[3]);
        *(float4*)&ad_out[w * 4] = make_float4(s[4], s[5], s[6], s[7]);
    }
}

__global__ void k_castT(const float* __restrict__ W, __hip_bfloat16* __restrict__ Wt,
                        int K, int Nw) {
    __shared__ float t[32][33];
    int k0 = blockIdx.x * 32, n0 = blockIdx.y * 32;
    int tx = threadIdx.x & 31, ty = threadIdx.x >> 5;
    for (int i = ty; i < 32; i += 8) t[i][tx] = W[(size_t)(k0 + i) * Nw + n0 + tx];
    __syncthreads();
    for (int i = ty; i < 32; i += 8)
        Wt[(size_t)(n0 + i) * K + k0 + tx] = __float2bfloat16(t[tx][i]);
}

// va8[c][0..3] = (W1[c, h*128:]·a_src[h]),  va8[c][4..7] = same with a_dst.
__global__ void k_va1(const float* __restrict__ W1, const float* __restrict__ asrc,
                      const float* __restrict__ adst, float* __restrict__ va8) {
    int t = threadIdx.x;        // 512 threads: c = t>>2, h = t&3
    int c = t >> 2, h = t & 3;
    const float* wrow = W1 + (size_t)c * 512 + h * 128;
    const float* av = asrc + h * 128;
    const float* dv = adst + h * 128;
    float vs = 0.f, vd = 0.f;
    for (int k = 0; k < 128; k++) {
        float wv = wrow[k];
        vs += wv * av[k];
        vd += wv * dv[k];
    }
    va8[c * 8 + h] = vs;
    va8[c * 8 + 4 + h] = vd;
}

// ------------------------- bf16 MFMA GEMM ----------------------------------
// C[row, cbase+col] = A[row, :K] @ Bt[col, :K]^T ; optional fused bias+ELU.
// ALPHA_H = 0: none.  ALPHA_H = 4: (BN=128, blockIdx.x==head) epilogue emits
// alpha[row*4+head] = C_block[row,:]·aTab[head].  ALPHA_H = 1: (BN=64) emits
// alpha[row] = C_block[row,:]·aTab.  Reduce: fr-lane shfl + LDS cross-wave.

template <int BM, int BN, bool FUSE, int ALPHA_H>
__global__ void __launch_bounds__(256) k_gemm_mfma(const __hip_bfloat16* __restrict__ A,
                                                   const __hip_bfloat16* __restrict__ Bt,
                                                   __hip_bfloat16* __restrict__ C,
                                                   int lda, int ldc, int K,
                                                   int hsA, int hsB, int hsC,
                                                   const float* __restrict__ bias,
                                                   const float* __restrict__ aSrcTab,
                                                   const float* __restrict__ aDstTab,
                                                   float* __restrict__ asOut,
                                                   float* __restrict__ adOut) {
    constexpr int BK = 64;
    constexpr int WM = BM / 2;
    constexpr int WN = BN / 2;
    constexpr int MREP = WM / 16;
    constexpr int NREP = WN / 16;

    __shared__ __hip_bfloat16 lds[(BM + BN) * BK];
    __hip_bfloat16* As = lds;
    __hip_bfloat16* Bs = lds + BM * BK;

    const int z = blockIdx.z;
    A += (size_t)z * hsA;
    Bt += (size_t)z * hsB;
    const int cbase = z * hsC;

    const int tid = threadIdx.x;
    const int wave = tid >> 6;
    const int lane = tid & 63;
    const int wm0 = (wave >> 1) * WM;
    const int wn0 = (wave & 1) * WN;
    const int m0 = blockIdx.y * BM;
    const int n0 = blockIdx.x * BN;
    const int fr = lane & 15;
    const int fq = lane >> 4;

    f32x4 acc[MREP][NREP] = {};

    for (int kt = 0; kt < K; kt += BK) {
        const __hip_bfloat16* srcA = A + (size_t)m0 * lda + kt;
#pragma unroll
        for (int it = 0; it < BM * 8 / 256; ++it) {
            int gb = it * 256 + wave * 64;
            int g = gb + lane;
            int row = g >> 3;
            int kg = (g & 7) ^ (row & 7);
            const __hip_bfloat16* gsrc = srcA + (size_t)row * lda + kg * 8;
            __builtin_amdgcn_global_load_lds(
                (const __attribute__((address_space(1))) void*)gsrc,
                (__attribute__((address_space(3))) void*)(As + gb * 8), 16, 0, 0);
        }
        const __hip_bfloat16* srcB = Bt + (size_t)n0 * K + kt;
#pragma unroll
        for (int it = 0; it < BN * 8 / 256; ++it) {
            int gb = it * 256 + wave * 64;
            int g = gb + lane;
            int row = g >> 3;
            int kg = (g & 7) ^ (row & 7);
            const __hip_bfloat16* gsrc = srcB + (size_t)row * K + kg * 8;
            __builtin_amdgcn_global_load_lds(
                (const __attribute__((address_space(1))) void*)gsrc,
                (__attribute__((address_space(3))) void*)(Bs + gb * 8), 16, 0, 0);
        }
        __syncthreads();

#pragma unroll
        for (int sl = 0; sl < 2; ++sl) {
            int ke = sl * 32 + fq * 8;
            bf16x8 af[MREP], bfr[NREP];
#pragma unroll
            for (int i = 0; i < MREP; ++i) {
                int row = wm0 + i * 16 + fr;
                int e = (row * BK + ke) ^ ((row & 7) << 3);
                af[i] = *(const bf16x8*)(As + e);
            }
#pragma unroll
            for (int j = 0; j < NREP; ++j) {
                int row = wn0 + j * 16 + fr;
                int e = (row * BK + ke) ^ ((row & 7) << 3);
                bfr[j] = *(const bf16x8*)(Bs + e);
            }
#pragma unroll
            for (int i = 0; i < MREP; ++i)
#pragma unroll
                for (int j = 0; j < NREP; ++j)
                    acc[i][j] = __builtin_amdgcn_mfma_f32_16x16x32_bf16(
                        af[i], bfr[j], acc[i][j], 0, 0, 0);
        }
        __syncthreads();
    }

#pragma unroll
    for (int i = 0; i < MREP; ++i) {
#pragma unroll
        for (int j = 0; j < NREP; ++j) {
            int colg = cbase + n0 + wn0 + j * 16 + fr;
#pragma unroll
            for (int r = 0; r < 4; ++r) {
                int rowg = m0 + wm0 + i * 16 + fq * 4 + r;
                float v = acc[i][j][r];
                if (FUSE) {
                    v += bias[colg];
                    v = v > 0.f ? v : expm1f(v);
                }
                C[(size_t)rowg * ldc + colg] = __float2bfloat16(v);
            }
        }
    }

    if constexpr (ALPHA_H > 0) {
        const int head = (ALPHA_H == 4) ? blockIdx.x : 0;
        float avs[NREP], avd[NREP];
#pragma unroll
        for (int j = 0; j < NREP; ++j) {
            int cl = wn0 + j * 16 + fr;
            avs[j] = aSrcTab[head * BN + cl];
            avd[j] = aDstTab[head * BN + cl];
        }
        float pa[MREP][4] = {};
        float pd_[MREP][4] = {};
#pragma unroll
        for (int i = 0; i < MREP; ++i)
#pragma unroll
            for (int j = 0; j < NREP; ++j)
#pragma unroll
                for (int r = 0; r < 4; ++r) {
                    pa[i][r] += acc[i][j][r] * avs[j];
                    pd_[i][r] += acc[i][j][r] * avd[j];
                }
        // reduce over the 16 fr lanes
#pragma unroll
        for (int off = 1; off <= 8; off <<= 1)
#pragma unroll
            for (int i = 0; i < MREP; ++i)
#pragma unroll
                for (int r = 0; r < 4; ++r) {
                    pa[i][r] += __shfl_xor(pa[i][r], off);
                    pd_[i][r] += __shfl_xor(pd_[i][r], off);
                }
        // cross-wave (column-half) add via LDS
        float* lds_a = (float*)lds;        // BM floats
        float* lds_d = lds_a + BM;         // BM floats
        if ((wave & 1) == 0 && fr == 0) {
#pragma unroll
            for (int i = 0; i < MREP; ++i)
#pragma unroll
                for (int r = 0; r < 4; ++r) {
                    int rl = wm0 + i * 16 + fq * 4 + r;
                    lds_a[rl] = pa[i][r];
                    lds_d[rl] = pd_[i][r];
                }
        }
        __syncthreads();
        if ((wave & 1) == 1 && fr == 0) {
#pragma unroll
            for (int i = 0; i < MREP; ++i)
#pragma unroll
                for (int r = 0; r < 4; ++r) {
                    int rl = wm0 + i * 16 + fq * 4 + r;
                    int rowg = m0 + rl;
                    if (ALPHA_H == 4) {
                        asOut[rowg * 4 + head] = lds_a[rl] + pa[i][r];
                        adOut[rowg * 4 + head] = lds_d[rl] + pd_[i][r];
                    } else {
                        asOut[rowg] = lds_a[rl] + pa[i][r];
                        adOut[rowg] = lds_d[rl] + pd_[i][r];
                    }
                }
        }
    }
}

// ------------------------- gathers ------------------------------------------
// L1: gather X rows (128 ch bf16); one wave per dst; lane owns 2 channels,
// accumulates all 4 heads. Edge weights computed INLINE cooperatively:
// lanes 0-15 compute w[edge q][head h] (q=lane>>2, h=lane&3) from as4/ad4,
// broadcast via constant-index shfl. Pads masked via cnt.

__global__ void k_gatherX(const __hip_bfloat16* __restrict__ xb,
                          const float* __restrict__ as4, const float* __restrict__ ad4,
                          const int* __restrict__ cnt, const int* __restrict__ rp,
                          const int* __restrict__ col, unsigned* __restrict__ out32, int N) {
    int w = (blockIdx.x * blockDim.x + threadIdx.x) >> 6;
    int lane = threadIdx.x & 63;
    if (w >= N) return;
    int d = w;
    int r0 = rp[d], r1 = rp[d + 1];
    int r1r = r0 + cnt[d];
    const unsigned* xp = (const unsigned*)xb;
    int q = (lane >> 2) & 3, hh = lane & 3;
    float adv = ad4[d * 4 + hh];

    float acc[8] = {};
    float ws0 = 0.f, ws1 = 0.f, ws2 = 0.f, ws3 = 0.f;
    for (int e = r0; e < r1; e += 4) {
        int4 c4 = *(const int4*)&col[e];
        // cooperative weight computation (meaningful in lanes 0..15)
        int sq = (q == 0) ? c4.x : (q == 1) ? c4.y : (q == 2) ? c4.z : c4.w;
        float av = as4[sq * 4 + hh];
        float wv = (e + q < r1r) ? __expf(leaky(av + adv)) : 0.f;
        float w00 = __shfl(wv, 0),  w01 = __shfl(wv, 1),  w02 = __shfl(wv, 2),  w03 = __shfl(wv, 3);
        float w10 = __shfl(wv, 4),  w11 = __shfl(wv, 5),  w12 = __shfl(wv, 6),  w13 = __shfl(wv, 7);
        float w20 = __shfl(wv, 8),  w21 = __shfl(wv, 9),  w22 = __shfl(wv, 10), w23 = __shfl(wv, 11);
        float w30 = __shfl(wv, 12), w31 = __shfl(wv, 13), w32 = __shfl(wv, 14), w33 = __shfl(wv, 15);
        unsigned v0 = xp[(size_t)c4.x * 64 + lane];
        unsigned v1 = xp[(size_t)c4.y * 64 + lane];
        unsigned v2 = xp[(size_t)c4.z * 64 + lane];
        unsigned v3 = xp[(size_t)c4.w * 64 + lane];
        ws0 += (w00 + w10) + (w20 + w30);
        ws1 += (w01 + w11) + (w21 + w31);
        ws2 += (w02 + w12) + (w22 + w32);
        ws3 += (w03 + w13) + (w23 + w33);
        float f0, f1;
        f0 = bflo(v0); f1 = bfhi(v0);
        acc[0] += w00 * f0; acc[1] += w00 * f1;
        acc[2] += w01 * f0; acc[3] += w01 * f1;
        acc[4] += w02 * f0; acc[5] += w02 * f1;
        acc[6] += w03 * f0; acc[7] += w03 * f1;
        f0 = bflo(v1); f1 = bfhi(v1);
        acc[0] += w10 * f0; acc[1] += w10 * f1;
        acc[2] += w11 * f0; acc[3] += w11 * f1;
        acc[4] += w12 * f0; acc[5] += w12 * f1;
        acc[6] += w13 * f0; acc[7] += w13 * f1;
        f0 = bflo(v2); f1 = bfhi(v2);
        acc[0] += w20 * f0; acc[1] += w20 * f1;
        acc[2] += w21 * f0; acc[3] += w21 * f1;
        acc[4] += w22 * f0; acc[5] += w22 * f1;
        acc[6] += w23 * f0; acc[7] += w23 * f1;
        f0 = bflo(v3); f1 = bfhi(v3);
        acc[0] += w30 * f0; acc[1] += w30 * f1;
        acc[2] += w31 * f0; acc[3] += w31 * f1;
        acc[4] += w32 * f0; acc[5] += w32 * f1;
        acc[6] += w33 * f0; acc[7] += w33 * f1;
    }
    float i0 = 1.f / (ws0 + 1e-16f), i1 = 1.f / (ws1 + 1e-16f);
    float i2 = 1.f / (ws2 + 1e-16f), i3 = 1.f / (ws3 + 1e-16f);
    size_t ob = (size_t)d * 256 + lane;
    out32[ob]       = pack2(acc[0] * i0, acc[1] * i0);
    out32[ob + 64]  = pack2(acc[2] * i1, acc[3] * i1);
    out32[ob + 128] = pack2(acc[4] * i2, acc[5] * i2);
    out32[ob + 192] = pack2(acc[6] * i3, acc[7] * i3);
}

// L2: full-row gather of h2 (512 ch), one wave per node, 16B/lane, unroll x4.
// Inline weights w = exp(leaky(as[s,hd] + ad[d,hd])); pad masked via cnt.

template <bool DO_ELU>
__global__ void k_gather512(const __hip_bfloat16* __restrict__ hfeat,
                            const float* __restrict__ as4, const float* __restrict__ ad4,
                            const int* __restrict__ cnt, const int* __restrict__ rp,
                            const int* __restrict__ col, const float* __restrict__ bias,
                            __hip_bfloat16* __restrict__ out, int N) {
    int w = (blockIdx.x * blockDim.x + threadIdx.x) >> 6;
    int lane = threadIdx.x & 63;
    if (w >= N) return;
    int d = w;
    int r0 = rp[d], r1 = rp[d + 1];      // quad-aligned
    int r1r = r0 + cnt[d];               // real edge end
    int hd = lane >> 4;
    float adv = ad4[d * 4 + hd];
    const uint4* hp = (const uint4*)hfeat;  // 64 uint4 per 512-ch row

    float acc[8] = {};
    float wsum = 0.f;
    for (int e = r0; e < r1; e += 4) {
        int4 c4 = *(const int4*)&col[e];
        float l0 = as4[c4.x * 4 + hd] + adv;
        float l1 = as4[c4.y * 4 + hd] + adv;
        float l2 = as4[c4.z * 4 + hd] + adv;
        float l3 = as4[c4.w * 4 + hd] + adv;
        uint4 v0 = hp[(size_t)c4.x * 64 + lane];
        uint4 v1 = hp[(size_t)c4.y * 64 + lane];
        uint4 v2 = hp[(size_t)c4.z * 64 + lane];
        uint4 v3 = hp[(size_t)c4.w * 64 + lane];
        float w0 = (e + 0 < r1r) ? __expf(leaky(l0)) : 0.f;
        float w1 = (e + 1 < r1r) ? __expf(leaky(l1)) : 0.f;
        float w2 = (e + 2 < r1r) ? __expf(leaky(l2)) : 0.f;
        float w3 = (e + 3 < r1r) ? __expf(leaky(l3)) : 0.f;
        wsum += (w0 + w1) + (w2 + w3);
        acc[0] += w0 * bflo(v0.x); acc[1] += w0 * bfhi(v0.x);
        acc[2] += w0 * bflo(v0.y); acc[3] += w0 * bfhi(v0.y);
        acc[4] += w0 * bflo(v0.z); acc[5] += w0 * bfhi(v0.z);
        acc[6] += w0 * bflo(v0.w); acc[7] += w0 * bfhi(v0.w);
        acc[0] += w1 * bflo(v1.x); acc[1] += w1 * bfhi(v1.x);
        acc[2] += w1 * bflo(v1.y); acc[3] += w1 * bfhi(v1.y);
        acc[4] += w1 * bflo(v1.z); acc[5] += w1 * bfhi(v1.z);
        acc[6] += w1 * bflo(v1.w); acc[7] += w1 * bfhi(v1.w);
        acc[0] += w2 * bflo(v2.x); acc[1] += w2 * bfhi(v2.x);
        acc[2] += w2 * bflo(v2.y); acc[3] += w2 * bfhi(v2.y);
        acc[4] += w2 * bflo(v2.z); acc[5] += w2 * bfhi(v2.z);
        acc[6] += w2 * bflo(v2.w); acc[7] += w2 * bfhi(v2.w);
        acc[0] += w3 * bflo(v3.x); acc[1] += w3 * bfhi(v3.x);
        acc[2] += w3 * bflo(v3.y); acc[3] += w3 * bfhi(v3.y);
        acc[4] += w3 * bflo(v3.z); acc[5] += w3 * bfhi(v3.z);
        acc[6] += w3 * bflo(v3.w); acc[7] += w3 * bfhi(v3.w);
    }

    float inv = 1.0f / (wsum + 1e-16f);
    __hip_bfloat16 tmp[8];
#pragma unroll
    for (int j = 0; j < 8; j++) {
        float v = acc[j] * inv + bias[lane * 8 + j];
        if (DO_ELU) v = v > 0.f ? v : expm1f(v);
        tmp[j] = __float2bfloat16(v);
    }
    *(float4*)(out + (size_t)d * 512 + lane * 8) = *(const float4*)tmp;
}

// L3: CT=64, H=1, f32 out: 16-lane groups each handle one edge, 4 edges/iter,
// inline weights (single head), pad masked via cnt.

__global__ void k_gather64(const __hip_bfloat16* __restrict__ hfeat,
                           const float* __restrict__ as1, const float* __restrict__ ad1,
                           const int* __restrict__ cnt, const int* __restrict__ rp,
                           const int* __restrict__ col, const float* __restrict__ bias,
                           float* __restrict__ out, int N) {
    int w = (blockIdx.x * blockDim.x + threadIdx.x) >> 6;
    int lane = threadIdx.x & 63;
    if (w >= N) return;
    int d = w;
    int r0 = rp[d], r1 = rp[d + 1];
    int r1r = r0 + cnt[d];
    float adv = ad1[d];
    int g = lane >> 4, cl = lane & 15;

    float a0 = 0.f, a1 = 0.f, a2 = 0.f, a3 = 0.f, wsum = 0.f;
    for (int e0 = r0; e0 < r1; e0 += 4) {
        int e = e0 + g;
        int s = col[e];
        float l = as1[s] + adv;
        uint2 q = *(const uint2*)(hfeat + (size_t)s * 64 + cl * 4);
        float wf = (e < r1r) ? __expf(leaky(l)) : 0.f;
        wsum += wf;
        a0 += wf * bflo(q.x);
        a1 += wf * bfhi(q.x);
        a2 += wf * bflo(q.y);
        a3 += wf * bfhi(q.y);
    }
#pragma unroll
    for (int off = 16; off <= 32; off <<= 1) {
        a0 += __shfl_xor(a0, off);
        a1 += __shfl_xor(a1, off);
        a2 += __shfl_xor(a2, off);
        a3 += __shfl_xor(a3, off);
        wsum += __shfl_xor(wsum, off);
    }
    if (g == 0) {
        float inv = 1.0f / (wsum + 1e-16f);
        float4 b4 = *(const float4*)&bias[cl * 4];
        float4 o = make_float4(a0 * inv + b4.x, a1 * inv + b4.y,
                               a2 * inv + b4.z, a3 * inv + b4.w);
        *(float4*)(out + (size_t)d * 64 + cl * 4) = o;
    }
}

// ------------------------- host launcher ------------------------------------

extern "C" void kernel_launch(void* const* d_in, const int* in_sizes, int n_in,
                              void* d_out, int out_size, void* d_ws, size_t ws_size,
                              hipStream_t stream) {
    const float* x   = (const float*)d_in[0];
    const int*   ei  = (const int*)d_in[1];
    const float* W1  = (const float*)d_in[2];
    const float* as1 = (const float*)d_in[3];
    const float* ad1 = (const float*)d_in[4];
    const float* b1  = (const float*)d_in[5];
    const float* W2  = (const float*)d_in[6];
    const float* as2 = (const float*)d_in[7];
    const float* ad2 = (const float*)d_in[8];
    const float* b2  = (const float*)d_in[9];
    const float* W3  = (const float*)d_in[10];
    const float* as3 = (const float*)d_in[11];
    const float* ad3 = (const float*)d_in[12];
    const float* b3  = (const float*)d_in[13];

    const int N = in_sizes[0] / 128;     // 50000
    const int E = in_sizes[1] / 2;       // 400000
    const int Etot = E + N;
    const int EP = (Etot + 3 * N + 255) & ~255;  // padded-edge upper bound
    const int Mp = (N + 127) & ~127;     // 50048

    char* ws = (char*)d_ws;
    size_t off = 0;
    auto alloc = [&](size_t bytes) -> void* {
        void* p = ws + off;
        off = (off + bytes + 255) & ~(size_t)255;
        return p;
    };
    __hip_bfloat16* hbuf = (__hip_bfloat16*)alloc((size_t)Mp * 512 * 2);  // h2 / h3
    __hip_bfloat16* fbuf = (__hip_bfloat16*)alloc((size_t)Mp * 512 * 2);  // f1 / f2
    __hip_bfloat16* xagg = (__hip_bfloat16*)alloc((size_t)Mp * 512 * 2);  // L1 gathered X
    __hip_bfloat16* xb   = (__hip_bfloat16*)alloc((size_t)Mp * 128 * 2);
    __hip_bfloat16* Wt1  = (__hip_bfloat16*)alloc((size_t)512 * 128 * 2);
    __hip_bfloat16* Wt2  = (__hip_bfloat16*)alloc((size_t)512 * 512 * 2);
    __hip_bfloat16* Wt3  = (__hip_bfloat16*)alloc((size_t)64 * 512 * 2);
    float* aS   = (float*)alloc((size_t)Mp * 4 * 4);
    float* aD   = (float*)alloc((size_t)Mp * 4 * 4);
    float* aS3  = (float*)alloc((size_t)Mp * 4);
    float* aD3  = (float*)alloc((size_t)Mp * 4);
    float* va8  = (float*)alloc(128 * 8 * 4);
    int* cnt  = (int*)alloc((size_t)N * 4);
    int* rp   = (int*)alloc((size_t)(N + 1) * 4);
    int* cur  = (int*)alloc((size_t)N * 4);
    int* col  = (int*)alloc((size_t)EP * 4);
    int* blks = (int*)alloc(64 * 4);

    // ---- CSR build (padded) ----
    hipMemsetAsync(cnt, 0, (size_t)N * 4, stream);
    int thr = 256;
    k_count<<<(Etot + thr - 1) / thr, thr, 0, stream>>>(ei, E, N, cnt);
    int nblk = (N + 1023) / 1024;
    k_scan1<<<nblk, 256, 0, stream>>>(cnt, N, rp, blks);
    k_scan3<<<(N + 255) / 256, 256, 0, stream>>>(rp, blks, cnt, N, nblk, cur, col);
    k_fill<<<(Etot + thr - 1) / thr, thr, 0, stream>>>(ei, E, N, cur, col);

    // ---- one-time casts + va + fused alpha1 ----
    {
        dim3 g1(128 / 32, 512 / 32);
        k_castT<<<g1, 256, 0, stream>>>(W1, Wt1, 128, 512);
        dim3 g2(512 / 32, 512 / 32);
        k_castT<<<g2, 256, 0, stream>>>(W2, Wt2, 512, 512);
        dim3 g3(512 / 32, 64 / 32);
        k_castT<<<g3, 256, 0, stream>>>(W3, Wt3, 512, 64);
        k_va1<<<1, 512, 0, stream>>>(W1, as1, ad1, va8);
        k_cast_alpha<<<(Mp + 3) / 4, 256, 0, stream>>>(x, xb, va8, aS, aD, N, Mp);
    }

    int gatBlocks = (N + 3) / 4;

    // ---- Layer 1: gather X (inline weights), fused per-head GEMM ----
    k_gatherX<<<gatBlocks, 256, 0, stream>>>(xb, aS, aD, cnt, rp, col,
                                             (unsigned*)xagg, N);
    {
        dim3 g(1, Mp / 128, 4);  // z = head
        k_gemm_mfma<128, 128, true, 0><<<g, 256, 0, stream>>>(
            xagg, Wt1, fbuf, 512, 512, 128, 128, 128 * 128, 128, b1,
            nullptr, nullptr, nullptr, nullptr);
    }

    // ---- Layer 2: GEMM w/ fused alpha2, full-row gather (+b2, ELU) ----
    {
        dim3 g(4, Mp / 128, 1);  // x = head (BN=128 per head)
        k_gemm_mfma<128, 128, false, 4><<<g, 256, 0, stream>>>(
            fbuf, Wt2, hbuf, 512, 512, 512, 0, 0, 0, nullptr,
            as2, ad2, aS, aD);
    }
    k_gather512<true><<<gatBlocks, 256, 0, stream>>>(hbuf, aS, aD, cnt, rp, col, b2,
                                                     fbuf, N);

    // ---- Layer 3: GEMM (BM=64) w/ fused alpha3, gather 64ch (+b3) ----
    {
        dim3 g(1, Mp / 64, 1);
        k_gemm_mfma<64, 64, false, 1><<<g, 256, 0, stream>>>(
            fbuf, Wt3, hbuf, 512, 64, 512, 0, 0, 0, nullptr,
            as3, ad3, aS3, aD3);
    }
    k_gather64<<<gatBlocks, 256, 0, stream>>>(hbuf, aS3, aD3, cnt, rp, col, b3,
                                              (float*)d_out, N);
}